// Round 2
// baseline (1669.877 us; speedup 1.0000x reference)
//
#include <hip/hip_runtime.h>

// Problem constants (fixed by the reference).
static constexpr int kB  = 2;
static constexpr int kL  = 4096;   // source sequence length
static constexpr int kD  = 1024;
static constexpr int kH  = 16;
static constexpr int kDH = 64;
static constexpr int kM  = 256;
static constexpr int kN  = kB * kL;              // 8192 deduplicated rows
static constexpr float kScale    = 0.35355339059327373f;  // DH^-0.25 = 64^-0.25
static constexpr float kInvSqrtM = 0.0625f;               // M^-0.5
static constexpr float kEps   = 1e-6f;
static constexpr float kLnEps = 1e-5f;

__device__ __forceinline__ float bf2f(unsigned short h) {
  union { unsigned int u; float f; } c;
  c.u = ((unsigned int)h) << 16;
  return c.f;
}
__device__ __forceinline__ unsigned short f2bf(float f) {
  union { float f; unsigned int u; } c;
  c.f = f;
  unsigned int u = c.u;
  u += 0x7fffu + ((u >> 16) & 1u);   // round-to-nearest-even
  return (unsigned short)(u >> 16);
}

// ---------------------------------------------------------------------------
// Tiled GEMM: C[N,P] = alpha * A[N,K] @ B[K,P], all f32 row-major.
// 128x128 tile, BK=16, 256 threads, 8x8 microtile, fp32 accumulate.
// ---------------------------------------------------------------------------
#define BM 128
#define BN 128
#define BK 16

__global__ __launch_bounds__(256) void gemm_f32(
    const float* __restrict__ A, const float* __restrict__ Bm,
    float* __restrict__ C, int N, int K, int P, float alpha)
{
  __shared__ float As[BK][BM + 4];
  __shared__ float Bs[BK][BN + 4];
  const int tid  = threadIdx.x;
  const int row0 = blockIdx.y * BM, col0 = blockIdx.x * BN;
  const int tx = tid & 15, ty = tid >> 4;
  const int arow = tid >> 1, ak = (tid & 1) * 8;   // A: 128 rows x 16 k
  const int bk = tid >> 4, bn = (tid & 15) * 8;    // B: 16 k x 128 n

  float acc[8][8];
#pragma unroll
  for (int i = 0; i < 8; ++i)
#pragma unroll
    for (int j = 0; j < 8; ++j) acc[i][j] = 0.f;

  for (int k0 = 0; k0 < K; k0 += BK) {
    __syncthreads();
    {
      const float* ap = A + (size_t)(row0 + arow) * K + (k0 + ak);
      float4 a0 = *(const float4*)ap;
      float4 a1 = *(const float4*)(ap + 4);
      As[ak + 0][arow] = a0.x; As[ak + 1][arow] = a0.y;
      As[ak + 2][arow] = a0.z; As[ak + 3][arow] = a0.w;
      As[ak + 4][arow] = a1.x; As[ak + 5][arow] = a1.y;
      As[ak + 6][arow] = a1.z; As[ak + 7][arow] = a1.w;
      const float* bp = Bm + (size_t)(k0 + bk) * P + (col0 + bn);
      float4 b0 = *(const float4*)bp;
      float4 b1 = *(const float4*)(bp + 4);
      Bs[bk][bn + 0] = b0.x; Bs[bk][bn + 1] = b0.y;
      Bs[bk][bn + 2] = b0.z; Bs[bk][bn + 3] = b0.w;
      Bs[bk][bn + 4] = b1.x; Bs[bk][bn + 5] = b1.y;
      Bs[bk][bn + 6] = b1.z; Bs[bk][bn + 7] = b1.w;
    }
    __syncthreads();
#pragma unroll
    for (int kk = 0; kk < BK; ++kk) {
      float a[8], b[8];
#pragma unroll
      for (int i = 0; i < 8; ++i) a[i] = As[kk][ty * 8 + i];
#pragma unroll
      for (int j = 0; j < 8; ++j) b[j] = Bs[kk][tx * 8 + j];
#pragma unroll
      for (int i = 0; i < 8; ++i)
#pragma unroll
        for (int j = 0; j < 8; ++j) acc[i][j] = fmaf(a[i], b[j], acc[i][j]);
    }
  }

#pragma unroll
  for (int i = 0; i < 8; ++i) {
    float* cp = C + (size_t)(row0 + ty * 8 + i) * P + col0 + tx * 8;
    float4 v0 = make_float4(alpha * acc[i][0], alpha * acc[i][1],
                            alpha * acc[i][2], alpha * acc[i][3]);
    float4 v1 = make_float4(alpha * acc[i][4], alpha * acc[i][5],
                            alpha * acc[i][6], alpha * acc[i][7]);
    ((float4*)cp)[0] = v0;
    ((float4*)cp)[1] = v1;
  }
}

// ---------------------------------------------------------------------------
// FAVOR features: F[bh, l, m] = exp(u.proj[h,m] - 0.5||u||^2 - rowmax) * M^-0.5
// U is [N, D] f32 (already scaled). Each thread owns one m; its proj row
// (64 f32) lives in registers. 64 rows per block.
// grid (B*H, L/64), 256 threads.
// ---------------------------------------------------------------------------
__global__ __launch_bounds__(256) void favor_kernel(
    const float* __restrict__ U, const float* __restrict__ proj,
    unsigned short* __restrict__ F)
{
  __shared__ float us[kDH];
  __shared__ float red[8];   // [0..3] wave maxes, [4] diag
  const int bh = blockIdx.x;
  const int h = bh & (kH - 1);
  const int b = bh >> 4;
  const int tid = threadIdx.x;
  const int lane = tid & 63, w = tid >> 6;

  float pr[kDH];
  {
    const float4* pb = (const float4*)(proj + ((size_t)h * kM + tid) * kDH);
#pragma unroll
    for (int i = 0; i < 16; ++i) {
      float4 t = pb[i];
      pr[i * 4 + 0] = t.x; pr[i * 4 + 1] = t.y;
      pr[i * 4 + 2] = t.z; pr[i * 4 + 3] = t.w;
    }
  }

  const int l0 = blockIdx.y * 64;
  for (int r = 0; r < 64; ++r) {
    const int l = l0 + r;
    __syncthreads();
    if (tid < 64) {
      float u = U[((size_t)(b * kL + l)) * kD + h * kDH + tid];
      us[tid] = u;
      float sq = u * u;
#pragma unroll
      for (int off = 32; off; off >>= 1) sq += __shfl_down(sq, off, 64);
      if (tid == 0) red[4] = 0.5f * sq;
    }
    __syncthreads();
    float d0 = 0.f, d1 = 0.f;
#pragma unroll
    for (int d = 0; d < kDH; d += 2) {
      d0 = fmaf(us[d],     pr[d],     d0);
      d1 = fmaf(us[d + 1], pr[d + 1], d1);
    }
    float dash = d0 + d1;
    float mx = dash;
#pragma unroll
    for (int off = 32; off; off >>= 1) mx = fmaxf(mx, __shfl_xor(mx, off, 64));
    if (lane == 0) red[w] = mx;
    __syncthreads();
    mx = fmaxf(fmaxf(red[0], red[1]), fmaxf(red[2], red[3]));
    float f = __expf(dash - red[4] - mx) * kInvSqrtM;
    F[((size_t)bh * kL + l) * kM + tid] = f2bf(f);
  }
}

// ---------------------------------------------------------------------------
// kv partials: per (bh, split) block accumulates kv[m,d] and ksum[m] over 512 l.
// 256 blocks (bh*8+split), thread = m, 64 f32 accumulators in registers.
// ---------------------------------------------------------------------------
__global__ __launch_bounds__(256) void kv_partial_kernel(
    const unsigned short* __restrict__ KF, const float* __restrict__ V,
    float* __restrict__ KVP, float* __restrict__ KSP)
{
  __shared__ float vs[16 * kDH];
  const int blk = blockIdx.x;
  const int bh = blk >> 3, split = blk & 7;
  const int b = bh >> 4, h = bh & 15;
  const int tid = threadIdx.x;
  float acc[kDH];
#pragma unroll
  for (int d = 0; d < kDH; ++d) acc[d] = 0.f;
  float ks = 0.f;
  const int l0 = split * 512;

  for (int lt = 0; lt < 512; lt += 16) {
    __syncthreads();
#pragma unroll
    for (int i = 0; i < 4; ++i) {
      int idx = i * 256 + tid;
      int r = idx >> 6, d = idx & 63;
      vs[idx] = V[((size_t)(b * kL + l0 + lt + r)) * kD + h * kDH + d];
    }
    __syncthreads();
#pragma unroll 4
    for (int r = 0; r < 16; ++r) {
      float f = bf2f(KF[((size_t)bh * kL + (l0 + lt + r)) * kM + tid]);
      ks += f;
      const float4* vv = (const float4*)&vs[r * kDH];
#pragma unroll
      for (int d4 = 0; d4 < 16; ++d4) {
        float4 v4 = vv[d4];
        acc[d4 * 4 + 0] = fmaf(f, v4.x, acc[d4 * 4 + 0]);
        acc[d4 * 4 + 1] = fmaf(f, v4.y, acc[d4 * 4 + 1]);
        acc[d4 * 4 + 2] = fmaf(f, v4.z, acc[d4 * 4 + 2]);
        acc[d4 * 4 + 3] = fmaf(f, v4.w, acc[d4 * 4 + 3]);
      }
    }
  }

  float4* op = (float4*)(KVP + ((size_t)blk) * (kM * kDH) + tid * kDH);
#pragma unroll
  for (int d4 = 0; d4 < 16; ++d4)
    op[d4] = make_float4(acc[d4 * 4 + 0], acc[d4 * 4 + 1],
                         acc[d4 * 4 + 2], acc[d4 * 4 + 3]);
  KSP[blk * kM + tid] = ks;
}

__global__ __launch_bounds__(256) void kv_reduce_kernel(
    const float* __restrict__ KVP, const float* __restrict__ KSP,
    float* __restrict__ KV, float* __restrict__ KSUM)
{
  const int gid = blockIdx.x * 256 + threadIdx.x;
  const int NKV = 32 * kM * kDH;   // 524288
  if (gid < NKV) {
    int bh = gid >> 14, idx = gid & 16383;
    float s = 0.f;
#pragma unroll
    for (int sp = 0; sp < 8; ++sp)
      s += KVP[((size_t)(bh * 8 + sp)) * 16384 + idx];
    KV[gid] = s;
  } else {
    int g = gid - NKV;
    if (g < 32 * kM) {
      int bh = g >> 8, m = g & 255;
      float s = 0.f;
#pragma unroll
      for (int sp = 0; sp < 8; ++sp) s += KSP[(bh * 8 + sp) * kM + m];
      KSUM[g] = s;
    }
  }
}

// ---------------------------------------------------------------------------
// attn: per row, attn[l,d] = (sum_m qf[l,m]*kv[m,d]) / (sum_m qf[l,m]*ksum[m] + eps)
// grid (B*H, L/32), 256 threads; wave w handles 8 rows, lane = d.
// kv staged bf16 in LDS (32 KB) to stay under the 64 KB static-LDS limit.
// ---------------------------------------------------------------------------
__global__ __launch_bounds__(256) void attn_kernel(
    const unsigned short* __restrict__ QF, const float* __restrict__ KV,
    const float* __restrict__ KSUM, float* __restrict__ ATTN)
{
  __shared__ unsigned short kvsh[kM * kDH];
  __shared__ float kss[kM];
  __shared__ float qrows[4][kM];
  const int bh = blockIdx.x, b = bh >> 4, h = bh & 15;
  const int tid = threadIdx.x, lane = tid & 63, w = tid >> 6;

#pragma unroll 8
  for (int i = 0; i < 64; ++i)
    kvsh[i * 256 + tid] = f2bf(KV[(size_t)bh * 16384 + i * 256 + tid]);
  kss[tid] = KSUM[bh * kM + tid];
  __syncthreads();

  const int l0 = blockIdx.y * 32 + w * 8;
  for (int r = 0; r < 8; ++r) {
    const int l = l0 + r;
    const ushort4 q4 = ((const ushort4*)(QF + ((size_t)bh * kL + l) * kM))[lane];
    qrows[w][lane * 4 + 0] = bf2f(q4.x);
    qrows[w][lane * 4 + 1] = bf2f(q4.y);
    qrows[w][lane * 4 + 2] = bf2f(q4.z);
    qrows[w][lane * 4 + 3] = bf2f(q4.w);

    const float* qr = qrows[w];
    float a0 = 0.f, a1 = 0.f, a2 = 0.f, a3 = 0.f, den = 0.f;
#pragma unroll 16
    for (int m = 0; m < 256; m += 4) {
      a0 = fmaf(qr[m + 0], bf2f(kvsh[(m + 0) * 64 + lane]), a0);
      a1 = fmaf(qr[m + 1], bf2f(kvsh[(m + 1) * 64 + lane]), a1);
      a2 = fmaf(qr[m + 2], bf2f(kvsh[(m + 2) * 64 + lane]), a2);
      a3 = fmaf(qr[m + 3], bf2f(kvsh[(m + 3) * 64 + lane]), a3);
    }
#pragma unroll
    for (int j = 0; j < 4; ++j) {
      int m = lane + j * 64;
      den = fmaf(qr[m], kss[m], den);
    }
#pragma unroll
    for (int off = 32; off; off >>= 1) den += __shfl_xor(den, off, 64);
    float z = 1.f / (den + kEps);
    float acc = (a0 + a1) + (a2 + a3);
    ATTN[((size_t)(b * kL + l)) * kD + h * kDH + lane] = acc * z;
  }
}

// ---------------------------------------------------------------------------
// GELU (exact) + LayerNorm + 2x nearest-neighbor duplicate write.
// One block per deduplicated row; writes out rows 2l and 2l+1.
// ---------------------------------------------------------------------------
__global__ __launch_bounds__(256) void gelu_ln_kernel(
    const float* __restrict__ Y, const float* __restrict__ lng,
    const float* __restrict__ lnb, float* __restrict__ OUT)
{
  __shared__ float r1[4], r2[4];
  const int n = blockIdx.x;            // 0..8191
  const int tid = threadIdx.x, lane = tid & 63, w = tid >> 6;

  float4 y4 = ((const float4*)(Y + (size_t)n * kD))[tid];
  float g0 = 0.5f * y4.x * (1.f + erff(y4.x * 0.70710678118654752f));
  float g1 = 0.5f * y4.y * (1.f + erff(y4.y * 0.70710678118654752f));
  float g2 = 0.5f * y4.z * (1.f + erff(y4.z * 0.70710678118654752f));
  float g3 = 0.5f * y4.w * (1.f + erff(y4.w * 0.70710678118654752f));

  float s  = (g0 + g1) + (g2 + g3);
  float ss = (g0 * g0 + g1 * g1) + (g2 * g2 + g3 * g3);
#pragma unroll
  for (int off = 32; off; off >>= 1) {
    s  += __shfl_xor(s, off, 64);
    ss += __shfl_xor(ss, off, 64);
  }
  if (lane == 0) { r1[w] = s; r2[w] = ss; }
  __syncthreads();
  s  = (r1[0] + r1[1]) + (r1[2] + r1[3]);
  ss = (r2[0] + r2[1]) + (r2[2] + r2[3]);
  float mu  = s * (1.f / (float)kD);
  float var = ss * (1.f / (float)kD) - mu * mu;
  float inv = rsqrtf(var + kLnEps);

  float4 gg = ((const float4*)lng)[tid];
  float4 bb = ((const float4*)lnb)[tid];
  float4 o;
  o.x = (g0 - mu) * inv * gg.x + bb.x;
  o.y = (g1 - mu) * inv * gg.y + bb.y;
  o.z = (g2 - mu) * inv * gg.z + bb.z;
  o.w = (g3 - mu) * inv * gg.w + bb.w;

  const int b = n >> 12, l = n & 4095;
  const int c = tid * 4;
  size_t base = ((size_t)(b * 8192 + 2 * l)) * kD + c;
  *(float4*)(OUT + base)      = o;   // out row 2l
  *(float4*)(OUT + base + kD) = o;   // out row 2l+1 (nearest-neighbor dup)
}

// ---------------------------------------------------------------------------
extern "C" void kernel_launch(void* const* d_in, const int* in_sizes, int n_in,
                              void* d_out, int out_size, void* d_ws, size_t ws_size,
                              hipStream_t stream)
{
  (void)in_sizes; (void)n_in; (void)out_size; (void)ws_size;
  const float* x    = (const float*)d_in[0];
  const float* Wq   = (const float*)d_in[1];
  const float* Wk   = (const float*)d_in[2];
  const float* Wv   = (const float*)d_in[3];
  const float* Wo   = (const float*)d_in[4];
  const float* proj = (const float*)d_in[5];
  const float* lng  = (const float*)d_in[6];
  const float* lnb  = (const float*)d_in[7];
  float* out = (float*)d_out;

  // Workspace layout (total 224 MiB):
  //   [0,32M)    Q      f32 [8192,1024]   (later aliased by ATTN f32)
  //   [32,64M)   K      f32               (later: KVP/KSP/KVb/KSUM)
  //   [64,96M)   V      f32               (later: Y f32)
  //   [96,160M)  QF     bf16 [32,4096,256]
  //   [160,224M) KF     bf16
  char* ws = (char*)d_ws;
  const size_t MB = 1024 * 1024;
  float* Q = (float*)(ws);
  float* K = (float*)(ws + 32 * MB);
  float* V = (float*)(ws + 64 * MB);
  unsigned short* QF = (unsigned short*)(ws + 96 * MB);
  unsigned short* KF = (unsigned short*)(ws + 160 * MB);
  // aliases (lifetimes disjoint):
  float* ATTN = Q;                            // written after Q is consumed
  float* KVP  = K;                            // 16 MiB, after K consumed
  float* KSP  = (float*)(ws + 32 * MB + 17 * MB);   // 256 KiB
  float* KVb  = (float*)(ws + 32 * MB + 18 * MB);   // 2 MiB
  float* KSUM = (float*)(ws + 32 * MB + 21 * MB);   // 32 KiB
  float* Y    = V;                            // written after V consumed

  dim3 ggemm(kD / BN, kN / BM);  // (8, 64)

  // 1) projections (q-side deduplicated: upsampled row pairs are identical)
  gemm_f32<<<ggemm, 256, 0, stream>>>(x, Wk, K, kN, kD, kD, kScale);
  gemm_f32<<<ggemm, 256, 0, stream>>>(x, Wv, V, kN, kD, kD, 1.0f);
  gemm_f32<<<ggemm, 256, 0, stream>>>(x, Wq, Q, kN, kD, kD, kScale);

  // 2) FAVOR features
  favor_kernel<<<dim3(kB * kH, kL / 64), 256, 0, stream>>>(Q, proj, QF);
  favor_kernel<<<dim3(kB * kH, kL / 64), 256, 0, stream>>>(K, proj, KF);

  // 3) kv / k_sum (split-K partials + reduce); K buffer is dead -> reuse
  kv_partial_kernel<<<256, 256, 0, stream>>>(KF, V, KVP, KSP);
  kv_reduce_kernel<<<(32 * kM * kDH + 32 * kM + 255) / 256, 256, 0, stream>>>(
      KVP, KSP, KVb, KSUM);

  // 4) attention read-out (writes ATTN, aliases Q)
  attn_kernel<<<dim3(kB * kH, kL / 32), 256, 0, stream>>>(QF, KVb, KSUM, ATTN);

  // 5) output projection (writes Y, aliases V)
  gemm_f32<<<ggemm, 256, 0, stream>>>(ATTN, Wo, Y, kN, kD, kD, 1.0f);

  // 6) GELU + LayerNorm + 2x duplicate write
  gelu_ln_kernel<<<kN, 256, 0, stream>>>(Y, lng, lnb, out);
}

// Round 3
// 698.583 us; speedup vs baseline: 2.3904x; 2.3904x over previous
//
#include <hip/hip_runtime.h>

// Problem constants (fixed by the reference).
static constexpr int kB  = 2;
static constexpr int kL  = 4096;   // source sequence length
static constexpr int kD  = 1024;
static constexpr int kH  = 16;
static constexpr int kDH = 64;
static constexpr int kM  = 256;
static constexpr int kN  = kB * kL;              // 8192 deduplicated rows
static constexpr float kScale    = 0.35355339059327373f;  // DH^-0.25
static constexpr float kInvSqrtM = 0.0625f;               // M^-0.5
static constexpr float kEps   = 1e-6f;
static constexpr float kLnEps = 1e-5f;

typedef __attribute__((ext_vector_type(8))) short short8;   // 8 bf16 (4 VGPRs)
typedef __attribute__((ext_vector_type(4))) float f32x4;

__device__ __forceinline__ float bf2f(unsigned short h) {
  union { unsigned int u; float f; } c;
  c.u = ((unsigned int)h) << 16;
  return c.f;
}
__device__ __forceinline__ unsigned short f2bf(float f) {
  union { float f; unsigned int u; } c;
  c.f = f;
  unsigned int u = c.u;
  u += 0x7fffu + ((u >> 16) & 1u);   // round-to-nearest-even
  return (unsigned short)(u >> 16);
}

// ---------------------------------------------------------------------------
// casts
// ---------------------------------------------------------------------------
__global__ __launch_bounds__(256) void cast_bf16_kernel(
    const float* __restrict__ in, unsigned short* __restrict__ out)
{
  const int i = blockIdx.x * 256 + threadIdx.x;
  float4 v = ((const float4*)in)[i];
  ushort4 o;
  o.x = f2bf(v.x); o.y = f2bf(v.y); o.z = f2bf(v.z); o.w = f2bf(v.w);
  ((ushort4*)out)[i] = o;
}

// WT[n][k] = bf16(W[k][n]), 1024x1024.
__global__ __launch_bounds__(256) void transpose_cast_kernel(
    const float* __restrict__ W, unsigned short* __restrict__ WT)
{
  __shared__ float tile[32][33];
  const int n0 = blockIdx.x * 32, k0 = blockIdx.y * 32;
  const int t = threadIdx.x, kk = t >> 5, nn = t & 31;
#pragma unroll
  for (int i = 0; i < 4; ++i)
    tile[kk + i * 8][nn] = W[(size_t)(k0 + kk + i * 8) * kD + n0 + nn];
  __syncthreads();
#pragma unroll
  for (int i = 0; i < 4; ++i)
    WT[(size_t)(n0 + kk + i * 8) * kD + k0 + nn] = f2bf(tile[nn][kk + i * 8]);
}

// ---------------------------------------------------------------------------
// MFMA GEMM: C[N,1024] = alpha * A[N,1024] @ B, with B given TRANSPOSED as
// BT[1024 n][1024 k], A/BT bf16. 128x128 tile, BK=32, 4 waves, 4x4 subtiles.
// OUT_BF16: write bf16, else f32.
// ---------------------------------------------------------------------------
template <int OUT_BF16>
__global__ __launch_bounds__(256) void gemm_mfma(
    const unsigned short* __restrict__ A, const unsigned short* __restrict__ BT,
    void* __restrict__ Cout, float alpha)
{
  __shared__ unsigned short As[128 * 40];   // padded stride 40 (2-way conflicts)
  __shared__ unsigned short Bs[128 * 40];
  const int tid = threadIdx.x, lane = tid & 63, w = tid >> 6;
  const int q = lane >> 4, c = lane & 15;
  const int wr = (w >> 1) * 64, wc = (w & 1) * 64;
  const int row0 = blockIdx.y * 128, col0 = blockIdx.x * 128;
  const int trow = tid >> 2, tc8 = (tid & 3) * 8;

  f32x4 acc[4][4];
#pragma unroll
  for (int i = 0; i < 4; ++i)
#pragma unroll
    for (int j = 0; j < 4; ++j) acc[i][j] = (f32x4)0.f;

  for (int k0 = 0; k0 < kD; k0 += 32) {
    __syncthreads();
#pragma unroll
    for (int i = 0; i < 2; ++i) {
      *(uint4*)&As[(trow + 64 * i) * 40 + tc8] =
          *(const uint4*)&A[(size_t)(row0 + trow + 64 * i) * kD + k0 + tc8];
      *(uint4*)&Bs[(trow + 64 * i) * 40 + tc8] =
          *(const uint4*)&BT[(size_t)(col0 + trow + 64 * i) * kD + k0 + tc8];
    }
    __syncthreads();
    short8 av[4], bv[4];
#pragma unroll
    for (int i = 0; i < 4; ++i)
      av[i] = *(const short8*)&As[(wr + i * 16 + c) * 40 + q * 8];
#pragma unroll
    for (int j = 0; j < 4; ++j)
      bv[j] = *(const short8*)&Bs[(wc + j * 16 + c) * 40 + q * 8];
#pragma unroll
    for (int i = 0; i < 4; ++i)
#pragma unroll
      for (int j = 0; j < 4; ++j)
        acc[i][j] = __builtin_amdgcn_mfma_f32_16x16x32_bf16(
            av[i], bv[j], acc[i][j], 0, 0, 0);
  }

#pragma unroll
  for (int i = 0; i < 4; ++i)
#pragma unroll
    for (int j = 0; j < 4; ++j)
#pragma unroll
      for (int r = 0; r < 4; ++r) {
        const int row = row0 + wr + i * 16 + q * 4 + r;
        const int col = col0 + wc + j * 16 + c;
        const float v = alpha * acc[i][j][r];
        if (OUT_BF16)
          ((unsigned short*)Cout)[(size_t)row * kD + col] = f2bf(v);
        else
          ((float*)Cout)[(size_t)row * kD + col] = v;
      }
}

// ---------------------------------------------------------------------------
// FAVOR features from bf16 U rows.
// grid (B*H, L/64), 256 threads; thread owns m, proj row in registers.
// ---------------------------------------------------------------------------
__global__ __launch_bounds__(256) void favor_kernel(
    const unsigned short* __restrict__ U, const float* __restrict__ proj,
    unsigned short* __restrict__ F)
{
  __shared__ float us[kDH];
  __shared__ float red[8];
  const int bh = blockIdx.x;
  const int h = bh & (kH - 1);
  const int b = bh >> 4;
  const int tid = threadIdx.x;
  const int lane = tid & 63, w = tid >> 6;

  float pr[kDH];
  {
    const float4* pb = (const float4*)(proj + ((size_t)h * kM + tid) * kDH);
#pragma unroll
    for (int i = 0; i < 16; ++i) {
      float4 t = pb[i];
      pr[i * 4 + 0] = t.x; pr[i * 4 + 1] = t.y;
      pr[i * 4 + 2] = t.z; pr[i * 4 + 3] = t.w;
    }
  }

  const int l0 = blockIdx.y * 64;
  for (int r = 0; r < 64; ++r) {
    const int l = l0 + r;
    __syncthreads();
    if (tid < 64) {
      float u = bf2f(U[((size_t)(b * kL + l)) * kD + h * kDH + tid]);
      us[tid] = u;
      float sq = u * u;
#pragma unroll
      for (int off = 32; off; off >>= 1) sq += __shfl_down(sq, off, 64);
      if (tid == 0) red[4] = 0.5f * sq;
    }
    __syncthreads();
    float d0 = 0.f, d1 = 0.f;
#pragma unroll
    for (int d = 0; d < kDH; d += 2) {
      d0 = fmaf(us[d],     pr[d],     d0);
      d1 = fmaf(us[d + 1], pr[d + 1], d1);
    }
    float dash = d0 + d1;
    float mx = dash;
#pragma unroll
    for (int off = 32; off; off >>= 1) mx = fmaxf(mx, __shfl_xor(mx, off, 64));
    if (lane == 0) red[w] = mx;
    __syncthreads();
    mx = fmaxf(fmaxf(red[0], red[1]), fmaxf(red[2], red[3]));
    float f = __expf(dash - red[4] - mx) * kInvSqrtM;
    F[((size_t)bh * kL + l) * kM + tid] = f2bf(f);
  }
}

// ---------------------------------------------------------------------------
// kv partials: per (bh, split) block accumulates kv[m,d] / ksum[m] over 256 l.
// 512 blocks (bh*16+split). KVP layout: [blk][d][m] (m contiguous).
// ---------------------------------------------------------------------------
__global__ __launch_bounds__(256) void kv_partial_kernel(
    const unsigned short* __restrict__ KF, const unsigned short* __restrict__ V,
    float* __restrict__ KVP, float* __restrict__ KSP)
{
  __shared__ float vs[16 * kDH];
  const int blk = blockIdx.x;
  const int bh = blk >> 4, split = blk & 15;
  const int b = bh >> 4, h = bh & 15;
  const int tid = threadIdx.x;
  float acc[kDH];
#pragma unroll
  for (int d = 0; d < kDH; ++d) acc[d] = 0.f;
  float ks = 0.f;
  const int l0 = split * 256;

  for (int lt = 0; lt < 256; lt += 16) {
    __syncthreads();
#pragma unroll
    for (int i = 0; i < 4; ++i) {
      int idx = i * 256 + tid;
      int r = idx >> 6, d = idx & 63;
      vs[idx] = bf2f(V[((size_t)(b * kL + l0 + lt + r)) * kD + h * kDH + d]);
    }
    __syncthreads();
#pragma unroll 4
    for (int r = 0; r < 16; ++r) {
      float f = bf2f(KF[((size_t)bh * kL + (l0 + lt + r)) * kM + tid]);
      ks += f;
      const float4* vv = (const float4*)&vs[r * kDH];
#pragma unroll
      for (int d4 = 0; d4 < 16; ++d4) {
        float4 v4 = vv[d4];
        acc[d4 * 4 + 0] = fmaf(f, v4.x, acc[d4 * 4 + 0]);
        acc[d4 * 4 + 1] = fmaf(f, v4.y, acc[d4 * 4 + 1]);
        acc[d4 * 4 + 2] = fmaf(f, v4.z, acc[d4 * 4 + 2]);
        acc[d4 * 4 + 3] = fmaf(f, v4.w, acc[d4 * 4 + 3]);
      }
    }
  }

#pragma unroll
  for (int d = 0; d < kDH; ++d)
    KVP[(size_t)blk * (kM * kDH) + d * kM + tid] = acc[d];
  KSP[blk * kM + tid] = ks;
}

// Reduce 16 splits -> KVT' bf16 [bh][80][256]: rows 0..63 = kv^T[d][m],
// row 64 = ksum[m], rows 65..79 = 0 (pad n-tile for the MFMA attn).
__global__ __launch_bounds__(256) void kv_reduce_kernel(
    const float* __restrict__ KVP, const float* __restrict__ KSP,
    unsigned short* __restrict__ KVT)
{
  const int blk = blockIdx.x;            // 32*80
  const int bh = blk / 80, n = blk - bh * 80;
  const int t = threadIdx.x;
  float s = 0.f;
  if (n < 64) {
#pragma unroll
    for (int sp = 0; sp < 16; ++sp)
      s += KVP[((size_t)(bh * 16 + sp)) * (kM * kDH) + n * kM + t];
  } else if (n == 64) {
#pragma unroll
    for (int sp = 0; sp < 16; ++sp) s += KSP[(bh * 16 + sp) * kM + t];
  }
  KVT[(size_t)bh * (80 * kM) + n * kM + t] = f2bf(s);
}

// ---------------------------------------------------------------------------
// MFMA attention read-out: per (b,h): C = QF[4096x256] @ KVT'^T, where n-tile
// 4 (cols 64..79) carries ksum -> denominator. Writes bf16 ATTN [N][1024].
// grid (32 bh, 32 l-tiles of 128), 256 threads.
// ---------------------------------------------------------------------------
__global__ __launch_bounds__(256) void attn_mfma(
    const unsigned short* __restrict__ QF, const unsigned short* __restrict__ KVT,
    unsigned short* __restrict__ ATTN)
{
  __shared__ unsigned short kvs[80 * 264];   // padded stride 264
  __shared__ unsigned short qs[128 * 40];
  const int bh = blockIdx.x, b = bh >> 4, h = bh & 15;
  const int l0 = blockIdx.y * 128;
  const int tid = threadIdx.x, lane = tid & 63, w = tid >> 6;
  const int q = lane >> 4, c = lane & 15;
  const int trow = tid >> 2, tc8 = (tid & 3) * 8;

#pragma unroll
  for (int it = 0; it < 20; ++it) {
    int idx4 = it * 256 + tid;           // ushort4 units, 5120 total
    int row = idx4 >> 6, col4 = idx4 & 63;
    *(ushort4*)&kvs[row * 264 + col4 * 4] =
        *(const ushort4*)&KVT[(size_t)bh * (80 * kM) + row * kM + col4 * 4];
  }

  f32x4 acc[2][5];
#pragma unroll
  for (int i = 0; i < 2; ++i)
#pragma unroll
    for (int j = 0; j < 5; ++j) acc[i][j] = (f32x4)0.f;

  for (int kk = 0; kk < 8; ++kk) {
    __syncthreads();
#pragma unroll
    for (int i = 0; i < 2; ++i)
      *(uint4*)&qs[(trow + 64 * i) * 40 + tc8] =
          *(const uint4*)&QF[((size_t)bh * kL + (l0 + trow + 64 * i)) * kM +
                             kk * 32 + tc8];
    __syncthreads();
    short8 bv[5];
#pragma unroll
    for (int j = 0; j < 5; ++j)
      bv[j] = *(const short8*)&kvs[(j * 16 + c) * 264 + kk * 32 + q * 8];
#pragma unroll
    for (int i = 0; i < 2; ++i) {
      short8 av = *(const short8*)&qs[(w * 32 + i * 16 + c) * 40 + q * 8];
#pragma unroll
      for (int j = 0; j < 5; ++j)
        acc[i][j] = __builtin_amdgcn_mfma_f32_16x16x32_bf16(
            av, bv[j], acc[i][j], 0, 0, 0);
    }
  }

#pragma unroll
  for (int i = 0; i < 2; ++i)
#pragma unroll
    for (int r = 0; r < 4; ++r) {
      float den = __shfl(acc[i][4][r], (lane & 48));
      float z = 1.f / (den + kEps);
      const int row = l0 + w * 32 + i * 16 + q * 4 + r;
      const size_t base = ((size_t)(b * kL + row)) * kD + h * kDH;
#pragma unroll
      for (int j = 0; j < 4; ++j)
        ATTN[base + j * 16 + c] = f2bf(acc[i][j][r] * z);
    }
}

// ---------------------------------------------------------------------------
// GELU (exact) + LayerNorm + 2x nearest-neighbor duplicate write.
// ---------------------------------------------------------------------------
__global__ __launch_bounds__(256) void gelu_ln_kernel(
    const float* __restrict__ Y, const float* __restrict__ lng,
    const float* __restrict__ lnb, float* __restrict__ OUT)
{
  __shared__ float r1[4], r2[4];
  const int n = blockIdx.x;
  const int tid = threadIdx.x, lane = tid & 63, w = tid >> 6;

  float4 y4 = ((const float4*)(Y + (size_t)n * kD))[tid];
  float g0 = 0.5f * y4.x * (1.f + erff(y4.x * 0.70710678118654752f));
  float g1 = 0.5f * y4.y * (1.f + erff(y4.y * 0.70710678118654752f));
  float g2 = 0.5f * y4.z * (1.f + erff(y4.z * 0.70710678118654752f));
  float g3 = 0.5f * y4.w * (1.f + erff(y4.w * 0.70710678118654752f));

  float s  = (g0 + g1) + (g2 + g3);
  float ss = (g0 * g0 + g1 * g1) + (g2 * g2 + g3 * g3);
#pragma unroll
  for (int off = 32; off; off >>= 1) {
    s  += __shfl_xor(s, off, 64);
    ss += __shfl_xor(ss, off, 64);
  }
  if (lane == 0) { r1[w] = s; r2[w] = ss; }
  __syncthreads();
  s  = (r1[0] + r1[1]) + (r1[2] + r1[3]);
  ss = (r2[0] + r2[1]) + (r2[2] + r2[3]);
  float mu  = s * (1.f / (float)kD);
  float var = ss * (1.f / (float)kD) - mu * mu;
  float inv = rsqrtf(var + kLnEps);

  float4 gg = ((const float4*)lng)[tid];
  float4 bb = ((const float4*)lnb)[tid];
  float4 o;
  o.x = (g0 - mu) * inv * gg.x + bb.x;
  o.y = (g1 - mu) * inv * gg.y + bb.y;
  o.z = (g2 - mu) * inv * gg.z + bb.z;
  o.w = (g3 - mu) * inv * gg.w + bb.w;

  const int b = n >> 12, l = n & 4095;
  const int cc = tid * 4;
  size_t base = ((size_t)(b * 8192 + 2 * l)) * kD + cc;
  *(float4*)(OUT + base)      = o;
  *(float4*)(OUT + base + kD) = o;
}

// ---------------------------------------------------------------------------
extern "C" void kernel_launch(void* const* d_in, const int* in_sizes, int n_in,
                              void* d_out, int out_size, void* d_ws, size_t ws_size,
                              hipStream_t stream)
{
  (void)in_sizes; (void)n_in; (void)out_size; (void)ws_size;
  const float* x    = (const float*)d_in[0];
  const float* Wq   = (const float*)d_in[1];
  const float* Wk   = (const float*)d_in[2];
  const float* Wv   = (const float*)d_in[3];
  const float* Wo   = (const float*)d_in[4];
  const float* proj = (const float*)d_in[5];
  const float* lng  = (const float*)d_in[6];
  const float* lnb  = (const float*)d_in[7];
  float* out = (float*)d_out;

  // Workspace layout (MB offsets, total ~202.5 MB):
  //  0   xb   bf16 [8192,1024]
  //  16  WqT / 18 WkT / 20 WvT / 22 WoT  bf16 [1024,1024] transposed
  //  24  Qb   bf16 (alias: KVP f32 spans [24,56) after favor)
  //  40  Kb   bf16 (alias: ATTN bf16 after kv consumed)
  //  56  Vb   bf16
  //  72  QF   bf16 [32,4096,256]  (alias: Y f32 [8192,1024] after attn)
  //  136 KF   bf16
  //  200 KSP  f32 [512,256]
  //  201 KVT  bf16 [32,80,256]
  char* ws = (char*)d_ws;
  const size_t MB = 1024 * 1024;
  unsigned short* xb  = (unsigned short*)(ws);
  unsigned short* WqT = (unsigned short*)(ws + 16 * MB);
  unsigned short* WkT = (unsigned short*)(ws + 18 * MB);
  unsigned short* WvT = (unsigned short*)(ws + 20 * MB);
  unsigned short* WoT = (unsigned short*)(ws + 22 * MB);
  unsigned short* Qb  = (unsigned short*)(ws + 24 * MB);
  unsigned short* Kb  = (unsigned short*)(ws + 40 * MB);
  unsigned short* Vb  = (unsigned short*)(ws + 56 * MB);
  unsigned short* QF  = (unsigned short*)(ws + 72 * MB);
  unsigned short* KF  = (unsigned short*)(ws + 136 * MB);
  float* KSP          = (float*)(ws + 200 * MB);
  unsigned short* KVT = (unsigned short*)(ws + 201 * MB);
  float* KVP          = (float*)(ws + 24 * MB);   // 32 MB, after Qb/Kb dead
  unsigned short* ATTN = Kb;                      // after KVP consumed
  float* Y            = (float*)(ws + 72 * MB);   // after QF consumed

  // 1) casts
  cast_bf16_kernel<<<(kN * kD) / 1024, 256, 0, stream>>>(x, xb);
  transpose_cast_kernel<<<dim3(32, 32), 256, 0, stream>>>(Wq, WqT);
  transpose_cast_kernel<<<dim3(32, 32), 256, 0, stream>>>(Wk, WkT);
  transpose_cast_kernel<<<dim3(32, 32), 256, 0, stream>>>(Wv, WvT);
  transpose_cast_kernel<<<dim3(32, 32), 256, 0, stream>>>(Wo, WoT);

  // 2) projections via MFMA (bf16 out)
  dim3 gg(8, 64);
  gemm_mfma<1><<<gg, 256, 0, stream>>>(xb, WkT, Kb, kScale);
  gemm_mfma<1><<<gg, 256, 0, stream>>>(xb, WvT, Vb, 1.0f);
  gemm_mfma<1><<<gg, 256, 0, stream>>>(xb, WqT, Qb, kScale);

  // 3) FAVOR features
  favor_kernel<<<dim3(kB * kH, kL / 64), 256, 0, stream>>>(Qb, proj, QF);
  favor_kernel<<<dim3(kB * kH, kL / 64), 256, 0, stream>>>(Kb, proj, KF);

  // 4) kv / k_sum (16-way split-K, then reduce to bf16 KVT')
  kv_partial_kernel<<<512, 256, 0, stream>>>(KF, Vb, KVP, KSP);
  kv_reduce_kernel<<<32 * 80, 256, 0, stream>>>(KVP, KSP, KVT);

  // 5) MFMA attention read-out -> bf16 ATTN
  attn_mfma<<<dim3(32, 32), 256, 0, stream>>>(QF, KVT, ATTN);

  // 6) output projection (f32 out)
  gemm_mfma<0><<<gg, 256, 0, stream>>>(ATTN, WoT, Y, 1.0f);

  // 7) GELU + LayerNorm + 2x duplicate write
  gelu_ln_kernel<<<kN, 256, 0, stream>>>(Y, lng, lnb, out);
}

// Round 4
// 424.385 us; speedup vs baseline: 3.9348x; 1.6461x over previous
//
#include <hip/hip_runtime.h>

// Problem constants (fixed by the reference).
static constexpr int kB  = 2;
static constexpr int kL  = 4096;   // source sequence length
static constexpr int kD  = 1024;
static constexpr int kH  = 16;
static constexpr int kDH = 64;
static constexpr int kM  = 256;
static constexpr int kN  = kB * kL;              // 8192 deduplicated rows
static constexpr float kScale    = 0.35355339059327373f;  // DH^-0.25
static constexpr float kInvSqrtM = 0.0625f;               // M^-0.5
static constexpr float kEps   = 1e-6f;
static constexpr float kLnEps = 1e-5f;

typedef __attribute__((ext_vector_type(8))) short short8;   // 8 bf16 (4 VGPRs)
typedef __attribute__((ext_vector_type(4))) float f32x4;

__device__ __forceinline__ float bf2f(unsigned short h) {
  union { unsigned int u; float f; } c;
  c.u = ((unsigned int)h) << 16;
  return c.f;
}
__device__ __forceinline__ unsigned short f2bf(float f) {
  union { float f; unsigned int u; } c;
  c.f = f;
  unsigned int u = c.u;
  u += 0x7fffu + ((u >> 16) & 1u);   // round-to-nearest-even
  return (unsigned short)(u >> 16);
}

// ---------------------------------------------------------------------------
// casts
// ---------------------------------------------------------------------------
__global__ __launch_bounds__(256) void cast_bf16_kernel(
    const float* __restrict__ in, unsigned short* __restrict__ out)
{
  const int i = blockIdx.x * 256 + threadIdx.x;
  float4 v = ((const float4*)in)[i];
  ushort4 o;
  o.x = f2bf(v.x); o.y = f2bf(v.y); o.z = f2bf(v.z); o.w = f2bf(v.w);
  ((ushort4*)out)[i] = o;
}

// WT[n][k] = bf16(W[k][n]), 1024x1024.
__global__ __launch_bounds__(256) void transpose_cast_kernel(
    const float* __restrict__ W, unsigned short* __restrict__ WT)
{
  __shared__ float tile[32][33];
  const int n0 = blockIdx.x * 32, k0 = blockIdx.y * 32;
  const int t = threadIdx.x, kk = t >> 5, nn = t & 31;
#pragma unroll
  for (int i = 0; i < 4; ++i)
    tile[kk + i * 8][nn] = W[(size_t)(k0 + kk + i * 8) * kD + n0 + nn];
  __syncthreads();
#pragma unroll
  for (int i = 0; i < 4; ++i)
    WT[(size_t)(n0 + kk + i * 8) * kD + k0 + nn] = f2bf(tile[nn][kk + i * 8]);
}

// ---------------------------------------------------------------------------
// MFMA GEMM: C[N,1024] = alpha * A[N,1024] @ B, with B given TRANSPOSED as
// BT[1024 n][1024 k], A/BT bf16. 128x128 tile, BK=32, 4 waves, 4x4 subtiles.
// ---------------------------------------------------------------------------
template <int OUT_BF16>
__global__ __launch_bounds__(256) void gemm_mfma(
    const unsigned short* __restrict__ A, const unsigned short* __restrict__ BT,
    void* __restrict__ Cout, float alpha)
{
  __shared__ unsigned short As[128 * 40];   // padded stride 40 (2-way conflicts)
  __shared__ unsigned short Bs[128 * 40];
  const int tid = threadIdx.x, lane = tid & 63, w = tid >> 6;
  const int q = lane >> 4, c = lane & 15;
  const int wr = (w >> 1) * 64, wc = (w & 1) * 64;
  const int row0 = blockIdx.y * 128, col0 = blockIdx.x * 128;
  const int trow = tid >> 2, tc8 = (tid & 3) * 8;

  f32x4 acc[4][4];
#pragma unroll
  for (int i = 0; i < 4; ++i)
#pragma unroll
    for (int j = 0; j < 4; ++j) acc[i][j] = (f32x4)0.f;

  for (int k0 = 0; k0 < kD; k0 += 32) {
    __syncthreads();
#pragma unroll
    for (int i = 0; i < 2; ++i) {
      *(uint4*)&As[(trow + 64 * i) * 40 + tc8] =
          *(const uint4*)&A[(size_t)(row0 + trow + 64 * i) * kD + k0 + tc8];
      *(uint4*)&Bs[(trow + 64 * i) * 40 + tc8] =
          *(const uint4*)&BT[(size_t)(col0 + trow + 64 * i) * kD + k0 + tc8];
    }
    __syncthreads();
    short8 av[4], bv[4];
#pragma unroll
    for (int i = 0; i < 4; ++i)
      av[i] = *(const short8*)&As[(wr + i * 16 + c) * 40 + q * 8];
#pragma unroll
    for (int j = 0; j < 4; ++j)
      bv[j] = *(const short8*)&Bs[(wc + j * 16 + c) * 40 + q * 8];
#pragma unroll
    for (int i = 0; i < 4; ++i)
#pragma unroll
      for (int j = 0; j < 4; ++j)
        acc[i][j] = __builtin_amdgcn_mfma_f32_16x16x32_bf16(
            av[i], bv[j], acc[i][j], 0, 0, 0);
  }

#pragma unroll
  for (int i = 0; i < 4; ++i)
#pragma unroll
    for (int j = 0; j < 4; ++j)
#pragma unroll
      for (int r = 0; r < 4; ++r) {
        const int row = row0 + wr + i * 16 + q * 4 + r;
        const int col = col0 + wc + j * 16 + c;
        const float v = alpha * acc[i][j][r];
        if (OUT_BF16)
          ((unsigned short*)Cout)[(size_t)row * kD + col] = f2bf(v);
        else
          ((float*)Cout)[(size_t)row * kD + col] = v;
      }
}

// ---------------------------------------------------------------------------
// FAVOR features via MFMA.
// Per block: (b,h), 128-row l-tile. dash[128x256] = U_tile[128x64] @ proj^T.
// Epilogue: rowmax (reg + shfl over the 16-lane col group), diag from staged
// U, exp, bf16 store. grid (32 bh, 32 l-tiles), 256 threads.
// ---------------------------------------------------------------------------
__global__ __launch_bounds__(256) void favor_mfma(
    const unsigned short* __restrict__ U, const unsigned short* __restrict__ projb,
    unsigned short* __restrict__ F)
{
  __shared__ unsigned short Us[128 * 72];    // 18 KB, pad 72
  __shared__ unsigned short Ps[256 * 72];    // 36 KB, pad 72
  __shared__ float diagp[256];
  __shared__ float diag[128];
  const int bh = blockIdx.x, b = bh >> 4, h = bh & 15;
  const int l0 = blockIdx.y * 128;
  const int tid = threadIdx.x, lane = tid & 63, w = tid >> 6;
  const int q = lane >> 4, c = lane & 15;
  const int wr = w * 32;

  // stage U tile: 128 rows x 64 bf16 (ushort8 per thread x4)
#pragma unroll
  for (int it = 0; it < 4; ++it) {
    int idx = it * 256 + tid;          // ushort8 units
    int row = idx >> 3, col8 = idx & 7;
    *(uint4*)&Us[row * 72 + col8 * 8] =
        *(const uint4*)&U[((size_t)(b * kL + l0 + row)) * kD + h * kDH + col8 * 8];
  }
  // stage proj[h]: 256 rows x 64 bf16 (x8)
#pragma unroll
  for (int it = 0; it < 8; ++it) {
    int idx = it * 256 + tid;
    int row = idx >> 3, col8 = idx & 7;
    *(uint4*)&Ps[row * 72 + col8 * 8] =
        *(const uint4*)&projb[((size_t)h * kM + row) * kDH + col8 * 8];
  }
  __syncthreads();

  // cooperative diag partials: thread -> (row = tid&127, half = tid>>7)
  {
    int row = tid & 127, half = tid >> 7;
    const unsigned short* ur = &Us[row * 72 + half * 32];
    float s = 0.f;
#pragma unroll
    for (int d8 = 0; d8 < 4; ++d8) {
      uint4 raw = *(const uint4*)&ur[d8 * 8];
      const unsigned short* us = (const unsigned short*)&raw;
#pragma unroll
      for (int j = 0; j < 8; ++j) { float v = bf2f(us[j]); s = fmaf(v, v, s); }
    }
    diagp[half * 128 + row] = s;
  }

  // MFMA: acc[i 2][j 16], K = 64 = 2 k-steps
  f32x4 acc[2][16];
#pragma unroll
  for (int i = 0; i < 2; ++i)
#pragma unroll
    for (int j = 0; j < 16; ++j) acc[i][j] = (f32x4)0.f;

#pragma unroll
  for (int ks = 0; ks < 2; ++ks) {
    short8 av[2];
#pragma unroll
    for (int i = 0; i < 2; ++i)
      av[i] = *(const short8*)&Us[(wr + i * 16 + c) * 72 + ks * 32 + q * 8];
#pragma unroll
    for (int j = 0; j < 16; ++j) {
      short8 bv = *(const short8*)&Ps[(j * 16 + c) * 72 + ks * 32 + q * 8];
#pragma unroll
      for (int i = 0; i < 2; ++i)
        acc[i][j] = __builtin_amdgcn_mfma_f32_16x16x32_bf16(
            av[i], bv, acc[i][j], 0, 0, 0);
    }
  }

  __syncthreads();
  if (tid < 128) diag[tid] = 0.5f * (diagp[tid] + diagp[128 + tid]);
  __syncthreads();

  // epilogue: per (i,r) row -> max over 256 cols, exp, store
#pragma unroll
  for (int i = 0; i < 2; ++i)
#pragma unroll
    for (int r = 0; r < 4; ++r) {
      const int lrow = wr + i * 16 + q * 4 + r;
      float mx = -3.4e38f;
#pragma unroll
      for (int j = 0; j < 16; ++j) mx = fmaxf(mx, acc[i][j][r]);
      mx = fmaxf(mx, __shfl_xor(mx, 1, 64));
      mx = fmaxf(mx, __shfl_xor(mx, 2, 64));
      mx = fmaxf(mx, __shfl_xor(mx, 4, 64));
      mx = fmaxf(mx, __shfl_xor(mx, 8, 64));
      const float base = diag[lrow] + mx;
      const size_t gbase = ((size_t)bh * kL + (l0 + lrow)) * kM;
#pragma unroll
      for (int j = 0; j < 16; ++j)
        F[gbase + j * 16 + c] = f2bf(__expf(acc[i][j][r] - base) * kInvSqrtM);
    }
}

// ---------------------------------------------------------------------------
// kv partials: per (bh, split) block accumulates kv[m,d] / ksum[m] over 256 l.
// 512 blocks (bh*16+split). KVP layout: [blk][d][m] (m contiguous).
// ---------------------------------------------------------------------------
__global__ __launch_bounds__(256) void kv_partial_kernel(
    const unsigned short* __restrict__ KF, const unsigned short* __restrict__ V,
    float* __restrict__ KVP, float* __restrict__ KSP)
{
  __shared__ float vs[16 * kDH];
  const int blk = blockIdx.x;
  const int bh = blk >> 4, split = blk & 15;
  const int b = bh >> 4, h = bh & 15;
  const int tid = threadIdx.x;
  float acc[kDH];
#pragma unroll
  for (int d = 0; d < kDH; ++d) acc[d] = 0.f;
  float ks = 0.f;
  const int l0 = split * 256;

  for (int lt = 0; lt < 256; lt += 16) {
    __syncthreads();
#pragma unroll
    for (int i = 0; i < 4; ++i) {
      int idx = i * 256 + tid;
      int r = idx >> 6, d = idx & 63;
      vs[idx] = bf2f(V[((size_t)(b * kL + l0 + lt + r)) * kD + h * kDH + d]);
    }
    __syncthreads();
#pragma unroll 4
    for (int r = 0; r < 16; ++r) {
      float f = bf2f(KF[((size_t)bh * kL + (l0 + lt + r)) * kM + tid]);
      ks += f;
      const float4* vv = (const float4*)&vs[r * kDH];
#pragma unroll
      for (int d4 = 0; d4 < 16; ++d4) {
        float4 v4 = vv[d4];
        acc[d4 * 4 + 0] = fmaf(f, v4.x, acc[d4 * 4 + 0]);
        acc[d4 * 4 + 1] = fmaf(f, v4.y, acc[d4 * 4 + 1]);
        acc[d4 * 4 + 2] = fmaf(f, v4.z, acc[d4 * 4 + 2]);
        acc[d4 * 4 + 3] = fmaf(f, v4.w, acc[d4 * 4 + 3]);
      }
    }
  }

#pragma unroll
  for (int d = 0; d < kDH; ++d)
    KVP[(size_t)blk * (kM * kDH) + d * kM + tid] = acc[d];
  KSP[blk * kM + tid] = ks;
}

// Reduce 16 splits -> KVT' bf16 [bh][80][256]: rows 0..63 = kv^T[d][m],
// row 64 = ksum[m], rows 65..79 = 0 (pad n-tile for the MFMA attn).
__global__ __launch_bounds__(256) void kv_reduce_kernel(
    const float* __restrict__ KVP, const float* __restrict__ KSP,
    unsigned short* __restrict__ KVT)
{
  const int blk = blockIdx.x;            // 32*80
  const int bh = blk / 80, n = blk - bh * 80;
  const int t = threadIdx.x;
  float s = 0.f;
  if (n < 64) {
#pragma unroll
    for (int sp = 0; sp < 16; ++sp)
      s += KVP[((size_t)(bh * 16 + sp)) * (kM * kDH) + n * kM + t];
  } else if (n == 64) {
#pragma unroll
    for (int sp = 0; sp < 16; ++sp) s += KSP[(bh * 16 + sp) * kM + t];
  }
  KVT[(size_t)bh * (80 * kM) + n * kM + t] = f2bf(s);
}

// ---------------------------------------------------------------------------
// MFMA attention read-out: per (b,h): C = QF[4096x256] @ KVT'^T, where n-tile
// 4 (cols 64..79) carries ksum -> denominator. Writes bf16 ATTN [N][1024].
// ---------------------------------------------------------------------------
__global__ __launch_bounds__(256) void attn_mfma(
    const unsigned short* __restrict__ QF, const unsigned short* __restrict__ KVT,
    unsigned short* __restrict__ ATTN)
{
  __shared__ unsigned short kvs[80 * 264];   // padded stride 264
  __shared__ unsigned short qs[128 * 40];
  const int bh = blockIdx.x, b = bh >> 4, h = bh & 15;
  const int l0 = blockIdx.y * 128;
  const int tid = threadIdx.x, lane = tid & 63, w = tid >> 6;
  const int q = lane >> 4, c = lane & 15;
  const int trow = tid >> 2, tc8 = (tid & 3) * 8;

#pragma unroll
  for (int it = 0; it < 20; ++it) {
    int idx4 = it * 256 + tid;           // ushort4 units, 5120 total
    int row = idx4 >> 6, col4 = idx4 & 63;
    *(ushort4*)&kvs[row * 264 + col4 * 4] =
        *(const ushort4*)&KVT[(size_t)bh * (80 * kM) + row * kM + col4 * 4];
  }

  f32x4 acc[2][5];
#pragma unroll
  for (int i = 0; i < 2; ++i)
#pragma unroll
    for (int j = 0; j < 5; ++j) acc[i][j] = (f32x4)0.f;

  for (int kk = 0; kk < 8; ++kk) {
    __syncthreads();
#pragma unroll
    for (int i = 0; i < 2; ++i)
      *(uint4*)&qs[(trow + 64 * i) * 40 + tc8] =
          *(const uint4*)&QF[((size_t)bh * kL + (l0 + trow + 64 * i)) * kM +
                             kk * 32 + tc8];
    __syncthreads();
    short8 bv[5];
#pragma unroll
    for (int j = 0; j < 5; ++j)
      bv[j] = *(const short8*)&kvs[(j * 16 + c) * 264 + kk * 32 + q * 8];
#pragma unroll
    for (int i = 0; i < 2; ++i) {
      short8 av = *(const short8*)&qs[(w * 32 + i * 16 + c) * 40 + q * 8];
#pragma unroll
      for (int j = 0; j < 5; ++j)
        acc[i][j] = __builtin_amdgcn_mfma_f32_16x16x32_bf16(
            av, bv[j], acc[i][j], 0, 0, 0);
    }
  }

#pragma unroll
  for (int i = 0; i < 2; ++i)
#pragma unroll
    for (int r = 0; r < 4; ++r) {
      float den = __shfl(acc[i][4][r], (lane & 48));
      float z = 1.f / (den + kEps);
      const int row = l0 + w * 32 + i * 16 + q * 4 + r;
      const size_t base = ((size_t)(b * kL + row)) * kD + h * kDH;
#pragma unroll
      for (int j = 0; j < 4; ++j)
        ATTN[base + j * 16 + c] = f2bf(acc[i][j][r] * z);
    }
}

// ---------------------------------------------------------------------------
// GELU (exact) + LayerNorm + 2x nearest-neighbor duplicate write.
// ---------------------------------------------------------------------------
__global__ __launch_bounds__(256) void gelu_ln_kernel(
    const float* __restrict__ Y, const float* __restrict__ lng,
    const float* __restrict__ lnb, float* __restrict__ OUT)
{
  __shared__ float r1[4], r2[4];
  const int n = blockIdx.x;
  const int tid = threadIdx.x, lane = tid & 63, w = tid >> 6;

  float4 y4 = ((const float4*)(Y + (size_t)n * kD))[tid];
  float g0 = 0.5f * y4.x * (1.f + erff(y4.x * 0.70710678118654752f));
  float g1 = 0.5f * y4.y * (1.f + erff(y4.y * 0.70710678118654752f));
  float g2 = 0.5f * y4.z * (1.f + erff(y4.z * 0.70710678118654752f));
  float g3 = 0.5f * y4.w * (1.f + erff(y4.w * 0.70710678118654752f));

  float s  = (g0 + g1) + (g2 + g3);
  float ss = (g0 * g0 + g1 * g1) + (g2 * g2 + g3 * g3);
#pragma unroll
  for (int off = 32; off; off >>= 1) {
    s  += __shfl_xor(s, off, 64);
    ss += __shfl_xor(ss, off, 64);
  }
  if (lane == 0) { r1[w] = s; r2[w] = ss; }
  __syncthreads();
  s  = (r1[0] + r1[1]) + (r1[2] + r1[3]);
  ss = (r2[0] + r2[1]) + (r2[2] + r2[3]);
  float mu  = s * (1.f / (float)kD);
  float var = ss * (1.f / (float)kD) - mu * mu;
  float inv = rsqrtf(var + kLnEps);

  float4 gg = ((const float4*)lng)[tid];
  float4 bb = ((const float4*)lnb)[tid];
  float4 o;
  o.x = (g0 - mu) * inv * gg.x + bb.x;
  o.y = (g1 - mu) * inv * gg.y + bb.y;
  o.z = (g2 - mu) * inv * gg.z + bb.z;
  o.w = (g3 - mu) * inv * gg.w + bb.w;

  const int b = n >> 12, l = n & 4095;
  const int cc = tid * 4;
  size_t base = ((size_t)(b * 8192 + 2 * l)) * kD + cc;
  *(float4*)(OUT + base)      = o;
  *(float4*)(OUT + base + kD) = o;
}

// ---------------------------------------------------------------------------
extern "C" void kernel_launch(void* const* d_in, const int* in_sizes, int n_in,
                              void* d_out, int out_size, void* d_ws, size_t ws_size,
                              hipStream_t stream)
{
  (void)in_sizes; (void)n_in; (void)out_size; (void)ws_size;
  const float* x    = (const float*)d_in[0];
  const float* Wq   = (const float*)d_in[1];
  const float* Wk   = (const float*)d_in[2];
  const float* Wv   = (const float*)d_in[3];
  const float* Wo   = (const float*)d_in[4];
  const float* proj = (const float*)d_in[5];
  const float* lng  = (const float*)d_in[6];
  const float* lnb  = (const float*)d_in[7];
  float* out = (float*)d_out;

  // Workspace layout (MB offsets, total ~203.5 MB):
  //  0   xb   bf16 [8192,1024]
  //  16  WqT / 18 WkT / 20 WvT / 22 WoT  bf16 [1024,1024] transposed
  //  24  Qb   bf16 (alias: KVP f32 spans [24,56) after favor)
  //  40  Kb   bf16 (alias: ATTN bf16 after kv consumed)
  //  56  Vb   bf16
  //  72  QF   bf16 [32,4096,256]  (alias: Y f32 [8192,1024] after attn)
  //  136 KF   bf16
  //  200 KSP  f32 [512,256]
  //  201 KVT  bf16 [32,80,256]
  //  203 projb bf16 [16,256,64]
  char* ws = (char*)d_ws;
  const size_t MB = 1024 * 1024;
  unsigned short* xb  = (unsigned short*)(ws);
  unsigned short* WqT = (unsigned short*)(ws + 16 * MB);
  unsigned short* WkT = (unsigned short*)(ws + 18 * MB);
  unsigned short* WvT = (unsigned short*)(ws + 20 * MB);
  unsigned short* WoT = (unsigned short*)(ws + 22 * MB);
  unsigned short* Qb  = (unsigned short*)(ws + 24 * MB);
  unsigned short* Kb  = (unsigned short*)(ws + 40 * MB);
  unsigned short* Vb  = (unsigned short*)(ws + 56 * MB);
  unsigned short* QF  = (unsigned short*)(ws + 72 * MB);
  unsigned short* KF  = (unsigned short*)(ws + 136 * MB);
  float* KSP          = (float*)(ws + 200 * MB);
  unsigned short* KVT = (unsigned short*)(ws + 201 * MB);
  unsigned short* projb = (unsigned short*)(ws + 203 * MB);
  float* KVP          = (float*)(ws + 24 * MB);   // 32 MB, after Qb/Kb dead
  unsigned short* ATTN = Kb;                      // after KVP consumed
  float* Y            = (float*)(ws + 72 * MB);   // after QF consumed

  // 1) casts
  cast_bf16_kernel<<<(kN * kD) / 1024, 256, 0, stream>>>(x, xb);
  cast_bf16_kernel<<<(kH * kM * kDH) / 1024, 256, 0, stream>>>(proj, projb);
  transpose_cast_kernel<<<dim3(32, 32), 256, 0, stream>>>(Wq, WqT);
  transpose_cast_kernel<<<dim3(32, 32), 256, 0, stream>>>(Wk, WkT);
  transpose_cast_kernel<<<dim3(32, 32), 256, 0, stream>>>(Wv, WvT);
  transpose_cast_kernel<<<dim3(32, 32), 256, 0, stream>>>(Wo, WoT);

  // 2) projections via MFMA (bf16 out)
  dim3 gg(8, 64);
  gemm_mfma<1><<<gg, 256, 0, stream>>>(xb, WkT, Kb, kScale);
  gemm_mfma<1><<<gg, 256, 0, stream>>>(xb, WvT, Vb, 1.0f);
  gemm_mfma<1><<<gg, 256, 0, stream>>>(xb, WqT, Qb, kScale);

  // 3) FAVOR features via MFMA
  favor_mfma<<<dim3(32, 32), 256, 0, stream>>>(Qb, projb, QF);
  favor_mfma<<<dim3(32, 32), 256, 0, stream>>>(Kb, projb, KF);

  // 4) kv / k_sum (16-way split-K, then reduce to bf16 KVT')
  kv_partial_kernel<<<512, 256, 0, stream>>>(KF, Vb, KVP, KSP);
  kv_reduce_kernel<<<32 * 80, 256, 0, stream>>>(KVP, KSP, KVT);

  // 5) MFMA attention read-out -> bf16 ATTN
  attn_mfma<<<dim3(32, 32), 256, 0, stream>>>(QF, KVT, ATTN);

  // 6) output projection (f32 out)
  gemm_mfma<0><<<gg, 256, 0, stream>>>(ATTN, WoT, Y, 1.0f);

  // 7) GELU + LayerNorm + 2x duplicate write
  gelu_ln_kernel<<<kN, 256, 0, stream>>>(Y, lng, lnb, out);
}

// Round 5
// 396.796 us; speedup vs baseline: 4.2084x; 1.0695x over previous
//
#include <hip/hip_runtime.h>

// Problem constants (fixed by the reference).
static constexpr int kB  = 2;
static constexpr int kL  = 4096;   // source sequence length
static constexpr int kD  = 1024;
static constexpr int kH  = 16;
static constexpr int kDH = 64;
static constexpr int kM  = 256;
static constexpr int kN  = kB * kL;              // 8192 deduplicated rows
static constexpr float kScale    = 0.35355339059327373f;  // DH^-0.25
static constexpr float kInvSqrtM = 0.0625f;               // M^-0.5
static constexpr float kEps   = 1e-6f;
static constexpr float kLnEps = 1e-5f;

typedef __attribute__((ext_vector_type(8))) short short8;   // 8 bf16 (4 VGPRs)
typedef __attribute__((ext_vector_type(4))) float f32x4;

__device__ __forceinline__ float bf2f(unsigned short h) {
  union { unsigned int u; float f; } c;
  c.u = ((unsigned int)h) << 16;
  return c.f;
}
__device__ __forceinline__ unsigned short f2bf(float f) {
  union { float f; unsigned int u; } c;
  c.f = f;
  unsigned int u = c.u;
  u += 0x7fffu + ((u >> 16) & 1u);   // round-to-nearest-even
  return (unsigned short)(u >> 16);
}

// ---------------------------------------------------------------------------
// casts
// ---------------------------------------------------------------------------
__global__ __launch_bounds__(256) void cast_bf16_kernel(
    const float* __restrict__ in, unsigned short* __restrict__ out)
{
  const int i = blockIdx.x * 256 + threadIdx.x;
  float4 v = ((const float4*)in)[i];
  ushort4 o;
  o.x = f2bf(v.x); o.y = f2bf(v.y); o.z = f2bf(v.z); o.w = f2bf(v.w);
  ((ushort4*)out)[i] = o;
}

// WT[n][k] = bf16(W[k][n]), 1024x1024.
__global__ __launch_bounds__(256) void transpose_cast_kernel(
    const float* __restrict__ W, unsigned short* __restrict__ WT)
{
  __shared__ float tile[32][33];
  const int n0 = blockIdx.x * 32, k0 = blockIdx.y * 32;
  const int t = threadIdx.x, kk = t >> 5, nn = t & 31;
#pragma unroll
  for (int i = 0; i < 4; ++i)
    tile[kk + i * 8][nn] = W[(size_t)(k0 + kk + i * 8) * kD + n0 + nn];
  __syncthreads();
#pragma unroll
  for (int i = 0; i < 4; ++i)
    WT[(size_t)(n0 + kk + i * 8) * kD + k0 + nn] = f2bf(tile[nn][kk + i * 8]);
}

// ---------------------------------------------------------------------------
// MFMA GEMM: C[N,1024] = alpha * A[N,1024] @ B, BT[1024 n][1024 k] given
// transposed, A/BT bf16. 128x128 tile, BK=32, 4 waves, 4x4 subtiles.
// OUT_MODE: 0 = f32 row-major, 1 = bf16 row-major,
//           2 = bf16 per-head transposed VT[b,h,d,l] (for the kv GEMM).
// ---------------------------------------------------------------------------
template <int OUT_MODE>
__global__ __launch_bounds__(256) void gemm_mfma(
    const unsigned short* __restrict__ A, const unsigned short* __restrict__ BT,
    void* __restrict__ Cout, float alpha)
{
  __shared__ unsigned short sm[2 * 128 * 40];   // As | Bs (pad stride 40)
  unsigned short* As = sm;
  unsigned short* Bs = sm + 128 * 40;
  const int tid = threadIdx.x, lane = tid & 63, w = tid >> 6;
  const int q = lane >> 4, c = lane & 15;
  const int wr = (w >> 1) * 64, wc = (w & 1) * 64;
  const int row0 = blockIdx.y * 128, col0 = blockIdx.x * 128;
  const int trow = tid >> 2, tc8 = (tid & 3) * 8;

  f32x4 acc[4][4];
#pragma unroll
  for (int i = 0; i < 4; ++i)
#pragma unroll
    for (int j = 0; j < 4; ++j) acc[i][j] = (f32x4)0.f;

  for (int k0 = 0; k0 < kD; k0 += 32) {
    __syncthreads();
#pragma unroll
    for (int i = 0; i < 2; ++i) {
      *(uint4*)&As[(trow + 64 * i) * 40 + tc8] =
          *(const uint4*)&A[(size_t)(row0 + trow + 64 * i) * kD + k0 + tc8];
      *(uint4*)&Bs[(trow + 64 * i) * 40 + tc8] =
          *(const uint4*)&BT[(size_t)(col0 + trow + 64 * i) * kD + k0 + tc8];
    }
    __syncthreads();
    short8 av[4], bv[4];
#pragma unroll
    for (int i = 0; i < 4; ++i)
      av[i] = *(const short8*)&As[(wr + i * 16 + c) * 40 + q * 8];
#pragma unroll
    for (int j = 0; j < 4; ++j)
      bv[j] = *(const short8*)&Bs[(wc + j * 16 + c) * 40 + q * 8];
#pragma unroll
    for (int i = 0; i < 4; ++i)
#pragma unroll
      for (int j = 0; j < 4; ++j)
        acc[i][j] = __builtin_amdgcn_mfma_f32_16x16x32_bf16(
            av[i], bv[j], acc[i][j], 0, 0, 0);
  }

  if (OUT_MODE != 2) {
#pragma unroll
    for (int i = 0; i < 4; ++i)
#pragma unroll
      for (int j = 0; j < 4; ++j)
#pragma unroll
        for (int r = 0; r < 4; ++r) {
          const int row = row0 + wr + i * 16 + q * 4 + r;
          const int col = col0 + wc + j * 16 + c;
          const float v = alpha * acc[i][j][r];
          if (OUT_MODE == 1)
            ((unsigned short*)Cout)[(size_t)row * kD + col] = f2bf(v);
          else
            ((float*)Cout)[(size_t)row * kD + col] = v;
        }
  } else {
    // Transposed per-head store: VT[(b*16+h)*64 + d][l], via LDS transpose.
    // T stride 136 (16B-aligned rows, 2-way-free write conflicts).
    unsigned short* T = sm;   // 64*136 = 8704 <= 10240 ushorts
    const int bq = row0 >> 12, l0 = row0 & 4095;
    __syncthreads();
#pragma unroll
    for (int hh = 0; hh < 2; ++hh) {
      if ((w & 1) == hh) {
#pragma unroll
        for (int i = 0; i < 4; ++i)
#pragma unroll
          for (int j = 0; j < 4; ++j) {
            ushort4 o;
            o.x = f2bf(acc[i][j][0]); o.y = f2bf(acc[i][j][1]);
            o.z = f2bf(acc[i][j][2]); o.w = f2bf(acc[i][j][3]);
            *(ushort4*)&T[(j * 16 + c) * 136 + wr + i * 16 + q * 4] = o;
          }
      }
      __syncthreads();
      {
        const int dl = tid >> 2, seg = tid & 3;
        const size_t dst =
            ((size_t)(bq * 1024 + col0 + hh * 64 + dl)) * (size_t)kL +
            l0 + seg * 32;
        uint4* gp = (uint4*)((unsigned short*)Cout + dst);
        const unsigned short* sp = &T[dl * 136 + seg * 32];
#pragma unroll
        for (int u = 0; u < 4; ++u) gp[u] = *(const uint4*)&sp[u * 8];
      }
      __syncthreads();
    }
  }
}

// ---------------------------------------------------------------------------
// FAVOR features via MFMA.
// Per block: (b,h), 128-row l-tile. dash[128x256] = U_tile[128x64] @ proj^T.
// TRANS=0: store F row-major [bh][l][m] (for QF).
// TRANS=1: store F transposed [bh][m][l] (KFT, feeds the kv MFMA GEMM).
// ---------------------------------------------------------------------------
template <int TRANS>
__global__ __launch_bounds__(256) void favor_mfma(
    const unsigned short* __restrict__ U, const unsigned short* __restrict__ projb,
    unsigned short* __restrict__ F)
{
  __shared__ unsigned short Us[128 * 72];    // 18 KB, pad 72
  __shared__ unsigned short Ps[256 * 72];    // 36 KB, pad 72 (reused as T)
  __shared__ float diagp[256];
  __shared__ float diag[128];
  const int bh = blockIdx.x, b = bh >> 4, h = bh & 15;
  const int l0 = blockIdx.y * 128;
  const int tid = threadIdx.x, lane = tid & 63, w = tid >> 6;
  const int q = lane >> 4, c = lane & 15;
  const int wr = w * 32;

#pragma unroll
  for (int it = 0; it < 4; ++it) {
    int idx = it * 256 + tid;          // ushort8 units
    int row = idx >> 3, col8 = idx & 7;
    *(uint4*)&Us[row * 72 + col8 * 8] =
        *(const uint4*)&U[((size_t)(b * kL + l0 + row)) * kD + h * kDH + col8 * 8];
  }
#pragma unroll
  for (int it = 0; it < 8; ++it) {
    int idx = it * 256 + tid;
    int row = idx >> 3, col8 = idx & 7;
    *(uint4*)&Ps[row * 72 + col8 * 8] =
        *(const uint4*)&projb[((size_t)h * kM + row) * kDH + col8 * 8];
  }
  __syncthreads();

  {
    int row = tid & 127, half = tid >> 7;
    const unsigned short* ur = &Us[row * 72 + half * 32];
    float s = 0.f;
#pragma unroll
    for (int d8 = 0; d8 < 4; ++d8) {
      uint4 raw = *(const uint4*)&ur[d8 * 8];
      const unsigned short* us = (const unsigned short*)&raw;
#pragma unroll
      for (int j = 0; j < 8; ++j) { float v = bf2f(us[j]); s = fmaf(v, v, s); }
    }
    diagp[half * 128 + row] = s;
  }

  f32x4 acc[2][16];
#pragma unroll
  for (int i = 0; i < 2; ++i)
#pragma unroll
    for (int j = 0; j < 16; ++j) acc[i][j] = (f32x4)0.f;

#pragma unroll
  for (int ks = 0; ks < 2; ++ks) {
    short8 av[2];
#pragma unroll
    for (int i = 0; i < 2; ++i)
      av[i] = *(const short8*)&Us[(wr + i * 16 + c) * 72 + ks * 32 + q * 8];
#pragma unroll
    for (int j = 0; j < 16; ++j) {
      short8 bv = *(const short8*)&Ps[(j * 16 + c) * 72 + ks * 32 + q * 8];
#pragma unroll
      for (int i = 0; i < 2; ++i)
        acc[i][j] = __builtin_amdgcn_mfma_f32_16x16x32_bf16(
            av[i], bv, acc[i][j], 0, 0, 0);
    }
  }

  __syncthreads();
  if (tid < 128) diag[tid] = 0.5f * (diagp[tid] + diagp[128 + tid]);
  __syncthreads();

  // exp epilogue: overwrite acc with exp(dash - diag - rowmax) * M^-0.5
#pragma unroll
  for (int i = 0; i < 2; ++i)
#pragma unroll
    for (int r = 0; r < 4; ++r) {
      const int lrow = wr + i * 16 + q * 4 + r;
      float mx = -3.4e38f;
#pragma unroll
      for (int j = 0; j < 16; ++j) mx = fmaxf(mx, acc[i][j][r]);
      mx = fmaxf(mx, __shfl_xor(mx, 1, 64));
      mx = fmaxf(mx, __shfl_xor(mx, 2, 64));
      mx = fmaxf(mx, __shfl_xor(mx, 4, 64));
      mx = fmaxf(mx, __shfl_xor(mx, 8, 64));
      const float base = diag[lrow] + mx;
      if (TRANS == 0) {
        const size_t gbase = ((size_t)bh * kL + (l0 + lrow)) * kM;
#pragma unroll
        for (int j = 0; j < 16; ++j)
          F[gbase + j * 16 + c] = f2bf(__expf(acc[i][j][r] - base) * kInvSqrtM);
      } else {
#pragma unroll
        for (int j = 0; j < 16; ++j)
          acc[i][j][r] = __expf(acc[i][j][r] - base) * kInvSqrtM;
      }
    }

  if (TRANS == 1) {
    // LDS-transpose each 128-m half, store KFT[bh*256 + m][l0..l0+128).
    unsigned short* T = Ps;   // 128*136 = 17408 <= 18432 ushorts
    __syncthreads();
#pragma unroll
    for (int mc = 0; mc < 2; ++mc) {
#pragma unroll
      for (int i = 0; i < 2; ++i)
#pragma unroll
        for (int jl = 0; jl < 8; ++jl) {
          const int jj = mc * 8 + jl;
          ushort4 o;
          o.x = f2bf(acc[i][jj][0]); o.y = f2bf(acc[i][jj][1]);
          o.z = f2bf(acc[i][jj][2]); o.w = f2bf(acc[i][jj][3]);
          *(ushort4*)&T[(jl * 16 + c) * 136 + wr + i * 16 + q * 4] = o;
        }
      __syncthreads();
      {
        const int ml = tid >> 1, seg = tid & 1;
        const size_t dst =
            ((size_t)(bh * kM + mc * 128 + ml)) * (size_t)kL + l0 + seg * 64;
        uint4* gp = (uint4*)(F + dst);
        const unsigned short* sp = &T[ml * 136 + seg * 64];
#pragma unroll
        for (int u = 0; u < 8; ++u) gp[u] = *(const uint4*)&sp[u * 8];
      }
      __syncthreads();
    }
  }
}

// ---------------------------------------------------------------------------
// kv via MFMA: per (bh, mtile, split): C[128 m][64 d] = KFT tile @ VT tile^T
// over 512 l. ksum[m] computed from the A-fragments (register + shfl).
// grid (32, 2, 8), 256 threads.
// ---------------------------------------------------------------------------
__global__ __launch_bounds__(256) void kv_mfma(
    const unsigned short* __restrict__ KFT, const unsigned short* __restrict__ VT,
    float* __restrict__ KVP, float* __restrict__ KSP)
{
  __shared__ unsigned short As[128 * 40];
  __shared__ unsigned short Bs[64 * 40];
  const int bh = blockIdx.x, mtile = blockIdx.y, split = blockIdx.z;
  const int tid = threadIdx.x, lane = tid & 63, w = tid >> 6;
  const int q = lane >> 4, c = lane & 15;
  const int l0 = split * 512;
  const unsigned short* Abase = KFT + ((size_t)(bh * kM + mtile * 128)) * kL + l0;
  const unsigned short* Bbase = VT + ((size_t)(bh * kDH)) * kL + l0;

  f32x4 acc[2][4];
#pragma unroll
  for (int i = 0; i < 2; ++i)
#pragma unroll
    for (int j = 0; j < 4; ++j) acc[i][j] = (f32x4)0.f;
  float ksr[2] = {0.f, 0.f};

  for (int k0 = 0; k0 < 512; k0 += 32) {
    __syncthreads();
#pragma unroll
    for (int it = 0; it < 2; ++it) {
      int idx = it * 256 + tid;               // 512 uint4 for A
      int row = idx >> 2, c8 = (idx & 3) * 8;
      *(uint4*)&As[row * 40 + c8] = *(const uint4*)&Abase[(size_t)row * kL + k0 + c8];
    }
    {
      int row = tid >> 2, c8 = (tid & 3) * 8;  // 256 uint4 for B
      *(uint4*)&Bs[row * 40 + c8] = *(const uint4*)&Bbase[(size_t)row * kL + k0 + c8];
    }
    __syncthreads();
    short8 av[2], bv[4];
#pragma unroll
    for (int i = 0; i < 2; ++i) {
      av[i] = *(const short8*)&As[(w * 32 + i * 16 + c) * 40 + q * 8];
#pragma unroll
      for (int e = 0; e < 8; ++e) ksr[i] += bf2f((unsigned short)av[i][e]);
    }
#pragma unroll
    for (int j = 0; j < 4; ++j)
      bv[j] = *(const short8*)&Bs[(j * 16 + c) * 40 + q * 8];
#pragma unroll
    for (int i = 0; i < 2; ++i)
#pragma unroll
      for (int j = 0; j < 4; ++j)
        acc[i][j] = __builtin_amdgcn_mfma_f32_16x16x32_bf16(
            av[i], bv[j], acc[i][j], 0, 0, 0);
  }

  const int blk = (bh * 2 + mtile) * 8 + split;
  float* op = KVP + (size_t)blk * (128 * 64);
#pragma unroll
  for (int i = 0; i < 2; ++i)
#pragma unroll
    for (int j = 0; j < 4; ++j)
#pragma unroll
      for (int r = 0; r < 4; ++r)
        op[(w * 32 + i * 16 + q * 4 + r) * 64 + j * 16 + c] = acc[i][j][r];

#pragma unroll
  for (int i = 0; i < 2; ++i) {
    float s = ksr[i];
    s += __shfl_xor(s, 16, 64);
    s += __shfl_xor(s, 32, 64);
    if (q == 0) KSP[blk * 128 + w * 32 + i * 16 + c] = s;
  }
}

// Reduce 8 splits -> KVT' bf16 [bh][80][256]: rows 0..63 = kv^T[d][m],
// row 64 = ksum[m], rows 65..79 = 0 (pad n-tile for the MFMA attn).
__global__ __launch_bounds__(256) void kv_reduce_kernel(
    const float* __restrict__ KVP, const float* __restrict__ KSP,
    unsigned short* __restrict__ KVT)
{
  const int blk = blockIdx.x;            // 32*80
  const int bh = blk / 80, n = blk - bh * 80;
  const int t = threadIdx.x;             // m
  const int mt = t >> 7, ml = t & 127;
  float s = 0.f;
  if (n < 64) {
#pragma unroll
    for (int sp = 0; sp < 8; ++sp)
      s += KVP[((size_t)((bh * 2 + mt) * 8 + sp)) * (128 * 64) + ml * 64 + n];
  } else if (n == 64) {
#pragma unroll
    for (int sp = 0; sp < 8; ++sp)
      s += KSP[((bh * 2 + mt) * 8 + sp) * 128 + ml];
  }
  KVT[(size_t)bh * (80 * kM) + n * kM + t] = f2bf(s);
}

// ---------------------------------------------------------------------------
// MFMA attention read-out: per (b,h): C = QF[4096x256] @ KVT'^T, where n-tile
// 4 (cols 64..79) carries ksum -> denominator. Writes bf16 ATTN [N][1024].
// ---------------------------------------------------------------------------
__global__ __launch_bounds__(256) void attn_mfma(
    const unsigned short* __restrict__ QF, const unsigned short* __restrict__ KVT,
    unsigned short* __restrict__ ATTN)
{
  __shared__ unsigned short kvs[80 * 264];   // padded stride 264
  __shared__ unsigned short qs[128 * 40];
  const int bh = blockIdx.x, b = bh >> 4, h = bh & 15;
  const int l0 = blockIdx.y * 128;
  const int tid = threadIdx.x, lane = tid & 63, w = tid >> 6;
  const int q = lane >> 4, c = lane & 15;
  const int trow = tid >> 2, tc8 = (tid & 3) * 8;

#pragma unroll
  for (int it = 0; it < 20; ++it) {
    int idx4 = it * 256 + tid;           // ushort4 units, 5120 total
    int row = idx4 >> 6, col4 = idx4 & 63;
    *(ushort4*)&kvs[row * 264 + col4 * 4] =
        *(const ushort4*)&KVT[(size_t)bh * (80 * kM) + row * kM + col4 * 4];
  }

  f32x4 acc[2][5];
#pragma unroll
  for (int i = 0; i < 2; ++i)
#pragma unroll
    for (int j = 0; j < 5; ++j) acc[i][j] = (f32x4)0.f;

  for (int kk = 0; kk < 8; ++kk) {
    __syncthreads();
#pragma unroll
    for (int i = 0; i < 2; ++i)
      *(uint4*)&qs[(trow + 64 * i) * 40 + tc8] =
          *(const uint4*)&QF[((size_t)bh * kL + (l0 + trow + 64 * i)) * kM +
                             kk * 32 + tc8];
    __syncthreads();
    short8 bv[5];
#pragma unroll
    for (int j = 0; j < 5; ++j)
      bv[j] = *(const short8*)&kvs[(j * 16 + c) * 264 + kk * 32 + q * 8];
#pragma unroll
    for (int i = 0; i < 2; ++i) {
      short8 av = *(const short8*)&qs[(w * 32 + i * 16 + c) * 40 + q * 8];
#pragma unroll
      for (int j = 0; j < 5; ++j)
        acc[i][j] = __builtin_amdgcn_mfma_f32_16x16x32_bf16(
            av, bv[j], acc[i][j], 0, 0, 0);
    }
  }

#pragma unroll
  for (int i = 0; i < 2; ++i)
#pragma unroll
    for (int r = 0; r < 4; ++r) {
      float den = __shfl(acc[i][4][r], (lane & 48));
      float z = 1.f / (den + kEps);
      const int row = l0 + w * 32 + i * 16 + q * 4 + r;
      const size_t base = ((size_t)(b * kL + row)) * kD + h * kDH;
#pragma unroll
      for (int j = 0; j < 4; ++j)
        ATTN[base + j * 16 + c] = f2bf(acc[i][j][r] * z);
    }
}

// ---------------------------------------------------------------------------
// GELU (exact) + LayerNorm + 2x nearest-neighbor duplicate write.
// ---------------------------------------------------------------------------
__global__ __launch_bounds__(256) void gelu_ln_kernel(
    const float* __restrict__ Y, const float* __restrict__ lng,
    const float* __restrict__ lnb, float* __restrict__ OUT)
{
  __shared__ float r1[4], r2[4];
  const int n = blockIdx.x;
  const int tid = threadIdx.x, lane = tid & 63, w = tid >> 6;

  float4 y4 = ((const float4*)(Y + (size_t)n * kD))[tid];
  float g0 = 0.5f * y4.x * (1.f + erff(y4.x * 0.70710678118654752f));
  float g1 = 0.5f * y4.y * (1.f + erff(y4.y * 0.70710678118654752f));
  float g2 = 0.5f * y4.z * (1.f + erff(y4.z * 0.70710678118654752f));
  float g3 = 0.5f * y4.w * (1.f + erff(y4.w * 0.70710678118654752f));

  float s  = (g0 + g1) + (g2 + g3);
  float ss = (g0 * g0 + g1 * g1) + (g2 * g2 + g3 * g3);
#pragma unroll
  for (int off = 32; off; off >>= 1) {
    s  += __shfl_xor(s, off, 64);
    ss += __shfl_xor(ss, off, 64);
  }
  if (lane == 0) { r1[w] = s; r2[w] = ss; }
  __syncthreads();
  s  = (r1[0] + r1[1]) + (r1[2] + r1[3]);
  ss = (r2[0] + r2[1]) + (r2[2] + r2[3]);
  float mu  = s * (1.f / (float)kD);
  float var = ss * (1.f / (float)kD) - mu * mu;
  float inv = rsqrtf(var + kLnEps);

  float4 gg = ((const float4*)lng)[tid];
  float4 bb = ((const float4*)lnb)[tid];
  float4 o;
  o.x = (g0 - mu) * inv * gg.x + bb.x;
  o.y = (g1 - mu) * inv * gg.y + bb.y;
  o.z = (g2 - mu) * inv * gg.z + bb.z;
  o.w = (g3 - mu) * inv * gg.w + bb.w;

  const int b = n >> 12, l = n & 4095;
  const int cc = tid * 4;
  size_t base = ((size_t)(b * 8192 + 2 * l)) * kD + cc;
  *(float4*)(OUT + base)      = o;
  *(float4*)(OUT + base + kD) = o;
}

// ---------------------------------------------------------------------------
extern "C" void kernel_launch(void* const* d_in, const int* in_sizes, int n_in,
                              void* d_out, int out_size, void* d_ws, size_t ws_size,
                              hipStream_t stream)
{
  (void)in_sizes; (void)n_in; (void)out_size; (void)ws_size;
  const float* x    = (const float*)d_in[0];
  const float* Wq   = (const float*)d_in[1];
  const float* Wk   = (const float*)d_in[2];
  const float* Wv   = (const float*)d_in[3];
  const float* Wo   = (const float*)d_in[4];
  const float* proj = (const float*)d_in[5];
  const float* lng  = (const float*)d_in[6];
  const float* lnb  = (const float*)d_in[7];
  float* out = (float*)d_out;

  // Workspace layout (MB offsets, total ~203.5 MB):
  //  0   xb    bf16 [8192,1024]
  //  16  WqT / 18 WkT / 20 WvT / 22 WoT  bf16 [1024,1024] transposed
  //  24  Qb    bf16 (alias: KVP f32 16 MB after favor-q)
  //  40  Kb    bf16 (alias: ATTN bf16 after favor-k)
  //  56  VT    bf16 [32 bh][64 d][4096 l]
  //  72  QF    bf16 [32,4096,256]  (alias: Y f32 after attn)
  //  136 KFT   bf16 [32 bh][256 m][4096 l]
  //  200 KSP   f32 [512][128]
  //  201 KVT   bf16 [32,80,256]
  //  203 projb bf16 [16,256,64]
  char* ws = (char*)d_ws;
  const size_t MB = 1024 * 1024;
  unsigned short* xb  = (unsigned short*)(ws);
  unsigned short* WqT = (unsigned short*)(ws + 16 * MB);
  unsigned short* WkT = (unsigned short*)(ws + 18 * MB);
  unsigned short* WvT = (unsigned short*)(ws + 20 * MB);
  unsigned short* WoT = (unsigned short*)(ws + 22 * MB);
  unsigned short* Qb  = (unsigned short*)(ws + 24 * MB);
  unsigned short* Kb  = (unsigned short*)(ws + 40 * MB);
  unsigned short* VT  = (unsigned short*)(ws + 56 * MB);
  unsigned short* QF  = (unsigned short*)(ws + 72 * MB);
  unsigned short* KFT = (unsigned short*)(ws + 136 * MB);
  float* KSP          = (float*)(ws + 200 * MB);
  unsigned short* KVT = (unsigned short*)(ws + 201 * MB);
  unsigned short* projb = (unsigned short*)(ws + 203 * MB);
  float* KVP          = (float*)(ws + 24 * MB);   // 16 MB, after Qb dead
  unsigned short* ATTN = Kb;                      // after favor-k consumed Kb
  float* Y            = (float*)(ws + 72 * MB);   // after QF consumed

  // 1) casts
  cast_bf16_kernel<<<(kN * kD) / 1024, 256, 0, stream>>>(x, xb);
  cast_bf16_kernel<<<(kH * kM * kDH) / 1024, 256, 0, stream>>>(proj, projb);
  transpose_cast_kernel<<<dim3(32, 32), 256, 0, stream>>>(Wq, WqT);
  transpose_cast_kernel<<<dim3(32, 32), 256, 0, stream>>>(Wk, WkT);
  transpose_cast_kernel<<<dim3(32, 32), 256, 0, stream>>>(Wv, WvT);
  transpose_cast_kernel<<<dim3(32, 32), 256, 0, stream>>>(Wo, WoT);

  // 2) projections via MFMA
  dim3 gg(8, 64);
  gemm_mfma<1><<<gg, 256, 0, stream>>>(xb, WkT, Kb, kScale);
  gemm_mfma<2><<<gg, 256, 0, stream>>>(xb, WvT, VT, 1.0f);   // per-head V^T
  gemm_mfma<1><<<gg, 256, 0, stream>>>(xb, WqT, Qb, kScale);

  // 3) FAVOR features via MFMA (K-side stored transposed)
  favor_mfma<0><<<dim3(32, 32), 256, 0, stream>>>(Qb, projb, QF);
  favor_mfma<1><<<dim3(32, 32), 256, 0, stream>>>(Kb, projb, KFT);

  // 4) kv / k_sum via MFMA (8-way split over l), reduce to bf16 KVT'
  kv_mfma<<<dim3(32, 2, 8), 256, 0, stream>>>(KFT, VT, KVP, KSP);
  kv_reduce_kernel<<<32 * 80, 256, 0, stream>>>(KVP, KSP, KVT);

  // 5) MFMA attention read-out -> bf16 ATTN
  attn_mfma<<<dim3(32, 32), 256, 0, stream>>>(QF, KVT, ATTN);

  // 6) output projection (f32 out)
  gemm_mfma<0><<<gg, 256, 0, stream>>>(ATTN, WoT, Y, 1.0f);

  // 7) GELU + LayerNorm + 2x duplicate write
  gelu_ln_kernel<<<kN, 256, 0, stream>>>(Y, lng, lnb, out);
}

// Round 7
// 390.234 us; speedup vs baseline: 4.2792x; 1.0168x over previous
//
#include <hip/hip_runtime.h>

// Problem constants (fixed by the reference).
static constexpr int kB  = 2;
static constexpr int kL  = 4096;   // source sequence length
static constexpr int kD  = 1024;
static constexpr int kH  = 16;
static constexpr int kDH = 64;
static constexpr int kM  = 256;
static constexpr int kN  = kB * kL;              // 8192 deduplicated rows
static constexpr float kScale    = 0.35355339059327373f;  // DH^-0.25
static constexpr float kInvSqrtM = 0.0625f;               // M^-0.5
static constexpr float kEps   = 1e-6f;
static constexpr float kLnEps = 1e-5f;

typedef __attribute__((ext_vector_type(8))) short short8;   // 8 bf16 (4 VGPRs)
typedef __attribute__((ext_vector_type(4))) float f32x4;

__device__ __forceinline__ float bf2f(unsigned short h) {
  union { unsigned int u; float f; } c;
  c.u = ((unsigned int)h) << 16;
  return c.f;
}
__device__ __forceinline__ unsigned short f2bf(float f) {
  union { float f; unsigned int u; } c;
  c.f = f;
  unsigned int u = c.u;
  u += 0x7fffu + ((u >> 16) & 1u);   // round-to-nearest-even
  return (unsigned short)(u >> 16);
}

// async global->LDS, 16 B per lane; LDS dest = wave-uniform base + lane*16.
__device__ __forceinline__ void gload_lds16(const unsigned short* g,
                                            unsigned short* l) {
  __builtin_amdgcn_global_load_lds(
      (const __attribute__((address_space(1))) unsigned int*)g,
      (__attribute__((address_space(3))) unsigned int*)l, 16, 0, 0);
}

// ---------------------------------------------------------------------------
// casts
// ---------------------------------------------------------------------------
__global__ __launch_bounds__(256) void cast_bf16_kernel(
    const float* __restrict__ in, unsigned short* __restrict__ out)
{
  const int i = blockIdx.x * 256 + threadIdx.x;
  float4 v = ((const float4*)in)[i];
  ushort4 o;
  o.x = f2bf(v.x); o.y = f2bf(v.y); o.z = f2bf(v.z); o.w = f2bf(v.w);
  ((ushort4*)out)[i] = o;
}

// WT[n][k] = bf16(W[k][n]), 1024x1024.
__global__ __launch_bounds__(256) void transpose_cast_kernel(
    const float* __restrict__ W, unsigned short* __restrict__ WT)
{
  __shared__ float tile[32][33];
  const int n0 = blockIdx.x * 32, k0 = blockIdx.y * 32;
  const int t = threadIdx.x, kk = t >> 5, nn = t & 31;
#pragma unroll
  for (int i = 0; i < 4; ++i)
    tile[kk + i * 8][nn] = W[(size_t)(k0 + kk + i * 8) * kD + n0 + nn];
  __syncthreads();
#pragma unroll
  for (int i = 0; i < 4; ++i)
    WT[(size_t)(n0 + kk + i * 8) * kD + k0 + nn] = f2bf(tile[nn][kk + i * 8]);
}

// ---------------------------------------------------------------------------
// MFMA GEMM (m97-style): C[N,1024] = alpha * A[N,1024] @ B, BT transposed.
// 128x128 tile, BK=32, unpadded LDS (64 B rows), global_load_lds width-16
// staging, 4 waves, 4x4 subtiles.
// OUT_MODE: 0 = f32 row-major, 1 = bf16 row-major,
//           2 = bf16 per-head transposed VT[b,h,d,l] (for the kv GEMM).
// ---------------------------------------------------------------------------
template <int OUT_MODE>
__global__ __launch_bounds__(256) void gemm_mfma(
    const unsigned short* __restrict__ A, const unsigned short* __restrict__ BT,
    void* __restrict__ Cout, float alpha)
{
  __shared__ unsigned short As[128 * 32];   // 8 KB, unpadded (m97 layout)
  __shared__ unsigned short Bs[128 * 32];
  __shared__ unsigned short Tbuf[OUT_MODE == 2 ? 64 * 136 : 1];
  const int tid = threadIdx.x, lane = tid & 63, w = tid >> 6;
  const int q = lane >> 4, c = lane & 15;
  const int wr = (w >> 1) * 64, wc = (w & 1) * 64;
  const int row0 = blockIdx.y * 128, col0 = blockIdx.x * 128;
  const int lrow = lane >> 2, lcol = (lane & 3) * 8;   // async-load lane map

  f32x4 acc[4][4];
#pragma unroll
  for (int i = 0; i < 4; ++i)
#pragma unroll
    for (int j = 0; j < 4; ++j) acc[i][j] = (f32x4)0.f;

  for (int k0 = 0; k0 < kD; k0 += 32) {
    // stage: each wave issues 2 A + 2 B async 1 KB loads (16 rows each)
#pragma unroll
    for (int i = 0; i < 2; ++i) {
      const int r0 = w * 32 + i * 16;
      gload_lds16(&A[(size_t)(row0 + r0 + lrow) * kD + k0 + lcol], &As[r0 * 32]);
      gload_lds16(&BT[(size_t)(col0 + r0 + lrow) * kD + k0 + lcol], &Bs[r0 * 32]);
    }
    __syncthreads();   // drains vmcnt(0) before barrier
    short8 av[4], bv[4];
#pragma unroll
    for (int i = 0; i < 4; ++i)
      av[i] = *(const short8*)&As[(wr + i * 16 + c) * 32 + q * 8];
#pragma unroll
    for (int j = 0; j < 4; ++j)
      bv[j] = *(const short8*)&Bs[(wc + j * 16 + c) * 32 + q * 8];
#pragma unroll
    for (int i = 0; i < 4; ++i)
#pragma unroll
      for (int j = 0; j < 4; ++j)
        acc[i][j] = __builtin_amdgcn_mfma_f32_16x16x32_bf16(
            av[i], bv[j], acc[i][j], 0, 0, 0);
    __syncthreads();
  }

  if (OUT_MODE != 2) {
#pragma unroll
    for (int i = 0; i < 4; ++i)
#pragma unroll
      for (int j = 0; j < 4; ++j)
#pragma unroll
        for (int r = 0; r < 4; ++r) {
          const int row = row0 + wr + i * 16 + q * 4 + r;
          const int col = col0 + wc + j * 16 + c;
          const float v = alpha * acc[i][j][r];
          if (OUT_MODE == 1)
            ((unsigned short*)Cout)[(size_t)row * kD + col] = f2bf(v);
          else
            ((float*)Cout)[(size_t)row * kD + col] = v;
        }
  } else {
    // Transposed per-head store: VT[(b*16+h)*64 + d][l], via LDS transpose.
    const int bq = row0 >> 12, l0 = row0 & 4095;
#pragma unroll
    for (int hh = 0; hh < 2; ++hh) {
      if ((w & 1) == hh) {
#pragma unroll
        for (int i = 0; i < 4; ++i)
#pragma unroll
          for (int j = 0; j < 4; ++j) {
            ushort4 o;
            o.x = f2bf(acc[i][j][0]); o.y = f2bf(acc[i][j][1]);
            o.z = f2bf(acc[i][j][2]); o.w = f2bf(acc[i][j][3]);
            *(ushort4*)&Tbuf[(j * 16 + c) * 136 + wr + i * 16 + q * 4] = o;
          }
      }
      __syncthreads();
      {
        const int dl = tid >> 2, seg = tid & 3;
        const size_t dst =
            ((size_t)(bq * 1024 + col0 + hh * 64 + dl)) * (size_t)kL +
            l0 + seg * 32;
        uint4* gp = (uint4*)((unsigned short*)Cout + dst);
        const unsigned short* sp = &Tbuf[dl * 136 + seg * 32];
#pragma unroll
        for (int u = 0; u < 4; ++u) gp[u] = *(const uint4*)&sp[u * 8];
      }
      __syncthreads();
    }
  }
}

// ---------------------------------------------------------------------------
// FAVOR features via MFMA. Per block: (b,h), 128-row l-tile.
// dash[128x256] = U_tile[128x64] @ proj[h]^T; proj fragments read straight
// from global (L2-hot), no LDS staging -> high occupancy.
// TRANS=0: store F row-major [bh][l][m] (QF).
// TRANS=1: store F transposed [bh][m][l] (KFT), via 64-row LDS chunks.
// ---------------------------------------------------------------------------
template <int TRANS>
__global__ __launch_bounds__(256) void favor_mfma(
    const unsigned short* __restrict__ U, const unsigned short* __restrict__ projb,
    unsigned short* __restrict__ F)
{
  __shared__ unsigned short Us[128 * 72];    // 18 KB, pad 72
  __shared__ unsigned short Tbuf[TRANS ? 64 * 136 : 1];
  __shared__ float diagp[256];
  __shared__ float diag[128];
  const int bh = blockIdx.x, b = bh >> 4, h = bh & 15;
  const int l0 = blockIdx.y * 128;
  const int tid = threadIdx.x, lane = tid & 63, w = tid >> 6;
  const int q = lane >> 4, c = lane & 15;
  const int wr = w * 32;

#pragma unroll
  for (int it = 0; it < 4; ++it) {
    int idx = it * 256 + tid;          // ushort8 units
    int row = idx >> 3, col8 = idx & 7;
    *(uint4*)&Us[row * 72 + col8 * 8] =
        *(const uint4*)&U[((size_t)(b * kL + l0 + row)) * kD + h * kDH + col8 * 8];
  }
  __syncthreads();

  {
    int row = tid & 127, half = tid >> 7;
    const unsigned short* ur = &Us[row * 72 + half * 32];
    float s = 0.f;
#pragma unroll
    for (int d8 = 0; d8 < 4; ++d8) {
      uint4 raw = *(const uint4*)&ur[d8 * 8];
      const unsigned short* us = (const unsigned short*)&raw;
#pragma unroll
      for (int j = 0; j < 8; ++j) { float v = bf2f(us[j]); s = fmaf(v, v, s); }
    }
    diagp[half * 128 + row] = s;
  }

  f32x4 acc[2][16];
#pragma unroll
  for (int i = 0; i < 2; ++i)
#pragma unroll
    for (int j = 0; j < 16; ++j) acc[i][j] = (f32x4)0.f;

#pragma unroll
  for (int ks = 0; ks < 2; ++ks) {
    short8 av[2];
#pragma unroll
    for (int i = 0; i < 2; ++i)
      av[i] = *(const short8*)&Us[(wr + i * 16 + c) * 72 + ks * 32 + q * 8];
#pragma unroll
    for (int jb = 0; jb < 2; ++jb) {
      short8 bv[8];
#pragma unroll
      for (int jl = 0; jl < 8; ++jl)
        bv[jl] = *(const short8*)&projb[
            ((size_t)(h * kM + (jb * 8 + jl) * 16 + c)) * kDH + ks * 32 + q * 8];
#pragma unroll
      for (int jl = 0; jl < 8; ++jl)
#pragma unroll
        for (int i = 0; i < 2; ++i)
          acc[i][jb * 8 + jl] = __builtin_amdgcn_mfma_f32_16x16x32_bf16(
              av[i], bv[jl], acc[i][jb * 8 + jl], 0, 0, 0);
    }
  }

  __syncthreads();
  if (tid < 128) diag[tid] = 0.5f * (diagp[tid] + diagp[128 + tid]);
  __syncthreads();

  // exp epilogue: acc <- exp(dash - diag - rowmax) * M^-0.5
#pragma unroll
  for (int i = 0; i < 2; ++i)
#pragma unroll
    for (int r = 0; r < 4; ++r) {
      const int lrow = wr + i * 16 + q * 4 + r;
      float mx = -3.4e38f;
#pragma unroll
      for (int j = 0; j < 16; ++j) mx = fmaxf(mx, acc[i][j][r]);
      mx = fmaxf(mx, __shfl_xor(mx, 1, 64));
      mx = fmaxf(mx, __shfl_xor(mx, 2, 64));
      mx = fmaxf(mx, __shfl_xor(mx, 4, 64));
      mx = fmaxf(mx, __shfl_xor(mx, 8, 64));
      const float base = diag[lrow] + mx;
      if (TRANS == 0) {
        const size_t gbase = ((size_t)bh * kL + (l0 + lrow)) * kM;
#pragma unroll
        for (int j = 0; j < 16; ++j)
          F[gbase + j * 16 + c] = f2bf(__expf(acc[i][j][r] - base) * kInvSqrtM);
      } else {
#pragma unroll
        for (int j = 0; j < 16; ++j)
          acc[i][j][r] = __expf(acc[i][j][r] - base) * kInvSqrtM;
      }
    }

  if (TRANS == 1) {
    // LDS-transpose 64-m chunks, store KFT[bh*256 + m][l0..l0+128).
#pragma unroll
    for (int mc = 0; mc < 4; ++mc) {
      __syncthreads();
#pragma unroll
      for (int jl = 0; jl < 4; ++jl) {
        const int jj = mc * 4 + jl;
#pragma unroll
        for (int i = 0; i < 2; ++i) {
          ushort4 o;
          o.x = f2bf(acc[i][jj][0]); o.y = f2bf(acc[i][jj][1]);
          o.z = f2bf(acc[i][jj][2]); o.w = f2bf(acc[i][jj][3]);
          *(ushort4*)&Tbuf[(jl * 16 + c) * 136 + wr + i * 16 + q * 4] = o;
        }
      }
      __syncthreads();
#pragma unroll
      for (int it = 0; it < 4; ++it) {       // 1024 uint4 = 64 rows x 16
        int idx = it * 256 + tid;
        int row = idx >> 4, col8 = idx & 15;
        *(uint4*)&F[((size_t)(bh * kM + mc * 64 + row)) * (size_t)kL +
                    l0 + col8 * 8] = *(const uint4*)&Tbuf[row * 136 + col8 * 8];
      }
    }
  }
}

// ---------------------------------------------------------------------------
// kv via MFMA: per (bh, mtile, split): C[128 m][64 d] = KFT tile @ VT tile^T
// over 512 l. ksum[m] from the A-fragments (register + shfl).
// ---------------------------------------------------------------------------
__global__ __launch_bounds__(256) void kv_mfma(
    const unsigned short* __restrict__ KFT, const unsigned short* __restrict__ VT,
    float* __restrict__ KVP, float* __restrict__ KSP)
{
  __shared__ unsigned short As[128 * 40];
  __shared__ unsigned short Bs[64 * 40];
  const int bh = blockIdx.x, mtile = blockIdx.y, split = blockIdx.z;
  const int tid = threadIdx.x, lane = tid & 63, w = tid >> 6;
  const int q = lane >> 4, c = lane & 15;
  const int l0 = split * 512;
  const unsigned short* Abase = KFT + ((size_t)(bh * kM + mtile * 128)) * kL + l0;
  const unsigned short* Bbase = VT + ((size_t)(bh * kDH)) * kL + l0;

  f32x4 acc[2][4];
#pragma unroll
  for (int i = 0; i < 2; ++i)
#pragma unroll
    for (int j = 0; j < 4; ++j) acc[i][j] = (f32x4)0.f;
  float ksr[2] = {0.f, 0.f};

  for (int k0 = 0; k0 < 512; k0 += 32) {
    __syncthreads();
#pragma unroll
    for (int it = 0; it < 2; ++it) {
      int idx = it * 256 + tid;               // 512 uint4 for A
      int row = idx >> 2, c8 = (idx & 3) * 8;
      *(uint4*)&As[row * 40 + c8] = *(const uint4*)&Abase[(size_t)row * kL + k0 + c8];
    }
    {
      int row = tid >> 2, c8 = (tid & 3) * 8;  // 256 uint4 for B
      *(uint4*)&Bs[row * 40 + c8] = *(const uint4*)&Bbase[(size_t)row * kL + k0 + c8];
    }
    __syncthreads();
    short8 av[2], bv[4];
#pragma unroll
    for (int i = 0; i < 2; ++i) {
      av[i] = *(const short8*)&As[(w * 32 + i * 16 + c) * 40 + q * 8];
#pragma unroll
      for (int e = 0; e < 8; ++e) ksr[i] += bf2f((unsigned short)av[i][e]);
    }
#pragma unroll
    for (int j = 0; j < 4; ++j)
      bv[j] = *(const short8*)&Bs[(j * 16 + c) * 40 + q * 8];
#pragma unroll
    for (int i = 0; i < 2; ++i)
#pragma unroll
      for (int j = 0; j < 4; ++j)
        acc[i][j] = __builtin_amdgcn_mfma_f32_16x16x32_bf16(
            av[i], bv[j], acc[i][j], 0, 0, 0);
  }

  const int blk = (bh * 2 + mtile) * 8 + split;
  float* op = KVP + (size_t)blk * (128 * 64);
#pragma unroll
  for (int i = 0; i < 2; ++i)
#pragma unroll
    for (int j = 0; j < 4; ++j)
#pragma unroll
      for (int r = 0; r < 4; ++r)
        op[(w * 32 + i * 16 + q * 4 + r) * 64 + j * 16 + c] = acc[i][j][r];

#pragma unroll
  for (int i = 0; i < 2; ++i) {
    float s = ksr[i];
    s += __shfl_xor(s, 16, 64);
    s += __shfl_xor(s, 32, 64);
    if (q == 0) KSP[blk * 128 + w * 32 + i * 16 + c] = s;
  }
}

// Reduce 8 splits -> KVT' bf16 [bh][80][256]: rows 0..63 = kv^T[d][m],
// row 64 = ksum[m], rows 65..79 = 0 (pad n-tile for the MFMA attn).
__global__ __launch_bounds__(256) void kv_reduce_kernel(
    const float* __restrict__ KVP, const float* __restrict__ KSP,
    unsigned short* __restrict__ KVT)
{
  const int blk = blockIdx.x;            // 32*80
  const int bh = blk / 80, n = blk - bh * 80;
  const int t = threadIdx.x;             // m
  const int mt = t >> 7, ml = t & 127;
  float s = 0.f;
  if (n < 64) {
#pragma unroll
    for (int sp = 0; sp < 8; ++sp)
      s += KVP[((size_t)((bh * 2 + mt) * 8 + sp)) * (128 * 64) + ml * 64 + n];
  } else if (n == 64) {
#pragma unroll
    for (int sp = 0; sp < 8; ++sp)
      s += KSP[((bh * 2 + mt) * 8 + sp) * 128 + ml];
  }
  KVT[(size_t)bh * (80 * kM) + n * kM + t] = f2bf(s);
}

// ---------------------------------------------------------------------------
// MFMA attention read-out: per (b,h): C = QF[4096x256] @ KVT'^T, n-tile 4
// carries ksum -> denominator. Writes bf16 ATTN [N][1024].
// ---------------------------------------------------------------------------
__global__ __launch_bounds__(256) void attn_mfma(
    const unsigned short* __restrict__ QF, const unsigned short* __restrict__ KVT,
    unsigned short* __restrict__ ATTN)
{
  __shared__ unsigned short kvs[80 * 264];   // padded stride 264
  __shared__ unsigned short qs[128 * 40];
  const int bh = blockIdx.x, b = bh >> 4, h = bh & 15;
  const int l0 = blockIdx.y * 128;
  const int tid = threadIdx.x, lane = tid & 63, w = tid >> 6;
  const int q = lane >> 4, c = lane & 15;
  const int trow = tid >> 2, tc8 = (tid & 3) * 8;

#pragma unroll
  for (int it = 0; it < 20; ++it) {
    int idx4 = it * 256 + tid;           // ushort4 units, 5120 total
    int row = idx4 >> 6, col4 = idx4 & 63;
    *(ushort4*)&kvs[row * 264 + col4 * 4] =
        *(const ushort4*)&KVT[(size_t)bh * (80 * kM) + row * kM + col4 * 4];
  }

  f32x4 acc[2][5];
#pragma unroll
  for (int i = 0; i < 2; ++i)
#pragma unroll
    for (int j = 0; j < 5; ++j) acc[i][j] = (f32x4)0.f;

  for (int kk = 0; kk < 8; ++kk) {
    __syncthreads();
#pragma unroll
    for (int i = 0; i < 2; ++i)
      *(uint4*)&qs[(trow + 64 * i) * 40 + tc8] =
          *(const uint4*)&QF[((size_t)bh * kL + (l0 + trow + 64 * i)) * kM +
                             kk * 32 + tc8];
    __syncthreads();
    short8 bv[5];
#pragma unroll
    for (int j = 0; j < 5; ++j)
      bv[j] = *(const short8*)&kvs[(j * 16 + c) * 264 + kk * 32 + q * 8];
#pragma unroll
    for (int i = 0; i < 2; ++i) {
      short8 av = *(const short8*)&qs[(w * 32 + i * 16 + c) * 40 + q * 8];
#pragma unroll
      for (int j = 0; j < 5; ++j)
        acc[i][j] = __builtin_amdgcn_mfma_f32_16x16x32_bf16(
            av, bv[j], acc[i][j], 0, 0, 0);
    }
  }

#pragma unroll
  for (int i = 0; i < 2; ++i)
#pragma unroll
    for (int r = 0; r < 4; ++r) {
      float den = __shfl(acc[i][4][r], (lane & 48));
      float z = 1.f / (den + kEps);
      const int row = l0 + w * 32 + i * 16 + q * 4 + r;
      const size_t base = ((size_t)(b * kL + row)) * kD + h * kDH;
#pragma unroll
      for (int j = 0; j < 4; ++j)
        ATTN[base + j * 16 + c] = f2bf(acc[i][j][r] * z);
    }
}

// ---------------------------------------------------------------------------
// GELU (exact) + LayerNorm + 2x nearest-neighbor duplicate write.
// ---------------------------------------------------------------------------
__global__ __launch_bounds__(256) void gelu_ln_kernel(
    const float* __restrict__ Y, const float* __restrict__ lng,
    const float* __restrict__ lnb, float* __restrict__ OUT)
{
  __shared__ float r1[4], r2[4];
  const int n = blockIdx.x;
  const int tid = threadIdx.x, lane = tid & 63, w = tid >> 6;

  float4 y4 = ((const float4*)(Y + (size_t)n * kD))[tid];
  float g0 = 0.5f * y4.x * (1.f + erff(y4.x * 0.70710678118654752f));
  float g1 = 0.5f * y4.y * (1.f + erff(y4.y * 0.70710678118654752f));
  float g2 = 0.5f * y4.z * (1.f + erff(y4.z * 0.70710678118654752f));
  float g3 = 0.5f * y4.w * (1.f + erff(y4.w * 0.70710678118654752f));

  float s  = (g0 + g1) + (g2 + g3);
  float ss = (g0 * g0 + g1 * g1) + (g2 * g2 + g3 * g3);
#pragma unroll
  for (int off = 32; off; off >>= 1) {
    s  += __shfl_xor(s, off, 64);
    ss += __shfl_xor(ss, off, 64);
  }
  if (lane == 0) { r1[w] = s; r2[w] = ss; }
  __syncthreads();
  s  = (r1[0] + r1[1]) + (r1[2] + r1[3]);
  ss = (r2[0] + r2[1]) + (r2[2] + r2[3]);
  float mu  = s * (1.f / (float)kD);
  float var = ss * (1.f / (float)kD) - mu * mu;
  float inv = rsqrtf(var + kLnEps);

  float4 gg = ((const float4*)lng)[tid];
  float4 bb = ((const float4*)lnb)[tid];
  float4 o;
  o.x = (g0 - mu) * inv * gg.x + bb.x;
  o.y = (g1 - mu) * inv * gg.y + bb.y;
  o.z = (g2 - mu) * inv * gg.z + bb.z;
  o.w = (g3 - mu) * inv * gg.w + bb.w;

  const int b = n >> 12, l = n & 4095;
  const int cc = tid * 4;
  size_t base = ((size_t)(b * 8192 + 2 * l)) * kD + cc;
  *(float4*)(OUT + base)      = o;
  *(float4*)(OUT + base + kD) = o;
}

// ---------------------------------------------------------------------------
extern "C" void kernel_launch(void* const* d_in, const int* in_sizes, int n_in,
                              void* d_out, int out_size, void* d_ws, size_t ws_size,
                              hipStream_t stream)
{
  (void)in_sizes; (void)n_in; (void)out_size; (void)ws_size;
  const float* x    = (const float*)d_in[0];
  const float* Wq   = (const float*)d_in[1];
  const float* Wk   = (const float*)d_in[2];
  const float* Wv   = (const float*)d_in[3];
  const float* Wo   = (const float*)d_in[4];
  const float* proj = (const float*)d_in[5];
  const float* lng  = (const float*)d_in[6];
  const float* lnb  = (const float*)d_in[7];
  float* out = (float*)d_out;

  // Workspace layout (MB offsets, total ~203.5 MB):
  //  0   xb    bf16 [8192,1024]
  //  16  WqT / 18 WkT / 20 WvT / 22 WoT  bf16 [1024,1024] transposed
  //  24  Qb    bf16 (alias: KVP f32 16 MB after favor-q)
  //  40  Kb    bf16 (alias: ATTN bf16 after favor-k)
  //  56  VT    bf16 [32 bh][64 d][4096 l]
  //  72  QF    bf16 [32,4096,256]  (alias: Y f32 after attn)
  //  136 KFT   bf16 [32 bh][256 m][4096 l]
  //  200 KSP   f32 [512][128]
  //  201 KVT   bf16 [32,80,256]
  //  203 projb bf16 [16,256,64]
  char* ws = (char*)d_ws;
  const size_t MB = 1024 * 1024;
  unsigned short* xb  = (unsigned short*)(ws);
  unsigned short* WqT = (unsigned short*)(ws + 16 * MB);
  unsigned short* WkT = (unsigned short*)(ws + 18 * MB);
  unsigned short* WvT = (unsigned short*)(ws + 20 * MB);
  unsigned short* WoT = (unsigned short*)(ws + 22 * MB);
  unsigned short* Qb  = (unsigned short*)(ws + 24 * MB);
  unsigned short* Kb  = (unsigned short*)(ws + 40 * MB);
  unsigned short* VT  = (unsigned short*)(ws + 56 * MB);
  unsigned short* QF  = (unsigned short*)(ws + 72 * MB);
  unsigned short* KFT = (unsigned short*)(ws + 136 * MB);
  float* KSP          = (float*)(ws + 200 * MB);
  unsigned short* KVT = (unsigned short*)(ws + 201 * MB);
  unsigned short* projb = (unsigned short*)(ws + 203 * MB);
  float* KVP          = (float*)(ws + 24 * MB);   // 16 MB, after Qb dead
  unsigned short* ATTN = Kb;                      // after favor-k consumed Kb
  float* Y            = (float*)(ws + 72 * MB);   // after QF consumed

  // 1) casts
  cast_bf16_kernel<<<(kN * kD) / 1024, 256, 0, stream>>>(x, xb);
  cast_bf16_kernel<<<(kH * kM * kDH) / 1024, 256, 0, stream>>>(proj, projb);
  transpose_cast_kernel<<<dim3(32, 32), 256, 0, stream>>>(Wq, WqT);
  transpose_cast_kernel<<<dim3(32, 32), 256, 0, stream>>>(Wk, WkT);
  transpose_cast_kernel<<<dim3(32, 32), 256, 0, stream>>>(Wv, WvT);
  transpose_cast_kernel<<<dim3(32, 32), 256, 0, stream>>>(Wo, WoT);

  // 2) projections via MFMA
  dim3 gg(8, 64);
  gemm_mfma<1><<<gg, 256, 0, stream>>>(xb, WkT, Kb, kScale);
  gemm_mfma<2><<<gg, 256, 0, stream>>>(xb, WvT, VT, 1.0f);   // per-head V^T
  gemm_mfma<1><<<gg, 256, 0, stream>>>(xb, WqT, Qb, kScale);

  // 3) FAVOR features via MFMA (K-side stored transposed)
  favor_mfma<0><<<dim3(32, 32), 256, 0, stream>>>(Qb, projb, QF);
  favor_mfma<1><<<dim3(32, 32), 256, 0, stream>>>(Kb, projb, KFT);

  // 4) kv / k_sum via MFMA (8-way split over l), reduce to bf16 KVT'
  kv_mfma<<<dim3(32, 2, 8), 256, 0, stream>>>(KFT, VT, KVP, KSP);
  kv_reduce_kernel<<<32 * 80, 256, 0, stream>>>(KVP, KSP, KVT);

  // 5) MFMA attention read-out -> bf16 ATTN
  attn_mfma<<<dim3(32, 32), 256, 0, stream>>>(QF, KVT, ATTN);

  // 6) output projection (f32 out)
  gemm_mfma<0><<<gg, 256, 0, stream>>>(ATTN, WoT, Y, 1.0f);

  // 7) GELU + LayerNorm + 2x duplicate write
  gelu_ln_kernel<<<kN, 256, 0, stream>>>(Y, lng, lnb, out);
}